// Round 13
// baseline (155.369 us; speedup 1.0000x reference)
//
#include <hip/hip_runtime.h>
#include <math.h>

#define TOTAL_G 17064
#define BATCHN  16
#define ALLF    0xFFFFFFFFFFFFFFFFull
// valid <=> score > 0.01f <=> scorebits > 0x3C23D70A <=> (key>>15) < 0xC3DC28F5
#define INVALID_HI 0xC3DC28F5u

typedef unsigned long long u64;
typedef unsigned int u32;
typedef unsigned short u16;

// ---- ws layout (bytes), total 3,664,256 ----
#define KEYS0_OFF   0          // u64[16][12800]  1,638,400
#define KEYS1_OFF   1638400    // u64[16][3200]     409,600
#define KEYS234_OFF 2048000    // u64[16][1088]     139,264
#define CLSI_OFF    2187264    // u16[16][17064]    546,048
#define NC_OFF      2733312    // int[32]: [16..31]=n512
#define T512_OFF    2733824    // u64[16]  (= Boundary-1; fallback predicate k > T512)
#define KR_OFF      2733952    // u64[16][512]       65,536
#define MSK_OFF     2799488    // u64[16][512*8]    524,288
#define SLOTK_OFF   3323776    // u64[16][100]       12,800
#define K512_OFF    3336576    // u64[16][512]       65,536
#define HIST_OFF    3402112    // u32[16][4096]     262,144 (memset 0 each launch)

struct Ptrs {
  const float *cls0,*cls1,*cls2,*cls3,*cls4;
  const float *reg0,*reg1,*reg2,*reg3,*reg4;
  const float *ctr0,*ctr1,*ctr2,*ctr3,*ctr4;
  const float *pos0,*pos1,*pos2,*pos3,*pos4;
  char *ws;
};

__device__ __forceinline__ float sigd(float x) {
  return (float)(1.0 / (1.0 + exp(-(double)x)));
}
__device__ __forceinline__ float dexp(float x) {
  return (float)exp((double)x);
}
__device__ __forceinline__ void levinfo(int gid, int& lev, int& idx, int& nl) {
  if      (gid < 12800) { lev=0; idx=gid;        nl=12800; }
  else if (gid < 16000) { lev=1; idx=gid-12800;  nl=3200;  }
  else if (gid < 16800) { lev=2; idx=gid-16000;  nl=800;   }
  else if (gid < 17008) { lev=3; idx=gid-16800;  nl=208;   }
  else                  { lev=4; idx=gid-17008;  nl=56;    }
}

__device__ __forceinline__ u64* krank_of(char* ws, int b) {
  return (u64*)(ws + KR_OFF + (size_t)b * 4096);
}
__device__ __forceinline__ u64* msk_of(char* ws, int b) {
  return (u64*)(ws + MSK_OFF + (size_t)b * 32768);
}
__device__ __forceinline__ u64* slotkey_of(char* ws, int b) {
  return (u64*)(ws + SLOTK_OFF + (size_t)b * 800);
}
__device__ __forceinline__ u64* k512_of(char* ws, int b) {
  return (u64*)(ws + K512_OFF + (size_t)b * 4096);
}

// exact box decode (identical everywhere -> deterministic)
__device__ __forceinline__ float4 decode_box(const Ptrs& P, int b, int gid) {
  int lev, idx, nl; levinfo(gid, lev, idx, nl);
  const float *rp, *pp;
  if      (lev == 0) { rp = P.reg0; pp = P.pos0; }
  else if (lev == 1) { rp = P.reg1; pp = P.pos1; }
  else if (lev == 2) { rp = P.reg2; pp = P.pos2; }
  else if (lev == 3) { rp = P.reg3; pp = P.pos3; }
  else               { rp = P.reg4; pp = P.pos4; }
  float4 rv = *(const float4*)(rp + (size_t)(b * nl + idx) * 4);
  float2 pv = *(const float2*)(pp + (size_t)(b * nl + idx) * 2);
  float e0 = dexp(rv.x), e1 = dexp(rv.y), e2 = dexp(rv.z), e3 = dexp(rv.w);
  float x1 = truncf(pv.x - e0), y1 = truncf(pv.y - e1);
  float x2 = truncf(pv.x + e2), y2 = truncf(pv.y + e3);
  x1 = fmaxf(x1, 0.0f); y1 = fmaxf(y1, 0.0f);
  x2 = fminf(x2, 1023.0f); y2 = fminf(y2, 799.0f);
  return make_float4(x1, y1, x2, y2);
}

// ---------------- K1: LDS-staged score / argmax / key + global histogram ----------------
__global__ __launch_bounds__(256) void k_score(Ptrs P) {
  __shared__ float4 sk4[64 * 20];   // 64 positions x 320 B = 20 KB
  int b = blockIdx.y;
  int tid = threadIdx.x;
  int p0 = blockIdx.x * 64;

  #pragma unroll
  for (int it = 0; it < 5; ++it) {
    int t4 = it * 256 + tid;
    int g = p0 + t4 / 20;
    if (g < TOTAL_G) {
      int sub = t4 - (t4 / 20) * 20;
      int lev, idx, nl; levinfo(g, lev, idx, nl);
      const float* clsb;
      if      (lev == 0) clsb = P.cls0;
      else if (lev == 1) clsb = P.cls1;
      else if (lev == 2) clsb = P.cls2;
      else if (lev == 3) clsb = P.cls3;
      else               clsb = P.cls4;
      sk4[t4] = ((const float4*)(clsb + (size_t)(b * nl + idx) * 80))[sub];
    }
  }
  __syncthreads();

  int lp = tid >> 2, q = tid & 3;
  int g = p0 + lp;
  if (g >= TOTAL_G) return;

  const float4* my4 = &sk4[lp * 20 + q * 5];
  float m = -INFINITY, m2 = -INFINITY; int mi = 0;
  #pragma unroll
  for (int k = 0; k < 5; ++k) {
    float4 v = my4[k];
    int base = q * 20 + 4 * k;
    if (v.x > m) { m2 = m; m = v.x; mi = base+0; } else if (v.x > m2) m2 = v.x;
    if (v.y > m) { m2 = m; m = v.y; mi = base+1; } else if (v.y > m2) m2 = v.y;
    if (v.z > m) { m2 = m; m = v.z; mi = base+2; } else if (v.z > m2) m2 = v.z;
    if (v.w > m) { m2 = m; m = v.w; mi = base+3; } else if (v.w > m2) m2 = v.w;
  }
  #pragma unroll
  for (int xw = 1; xw <= 2; xw <<= 1) {
    float om  = __shfl_xor(m,  xw);
    float om2 = __shfl_xor(m2, xw);
    int   omi = __shfl_xor(mi, xw);
    bool take = (om > m) || (om == m && omi < mi);
    float lm  = take ? m : om;
    float wm2 = take ? om2 : m2;
    if (take) { m = om; mi = omi; }
    m2 = fmaxf(lm, wm2);
  }

  float thr = fminf(m - 1e-3f, 9.0f);
  float pmax; int ci;
  if (m2 >= thr) {
    // rare exact path: per-element sigmoid argmax among candidates >= thr
    float pv = -1.0f; int pi = 0x7fffffff;
    #pragma unroll 1
    for (int k = 0; k < 5; ++k) {
      float4 v = my4[k];
      float xs[4] = {v.x, v.y, v.z, v.w};
      #pragma unroll
      for (int e = 0; e < 4; ++e) {
        if (xs[e] >= thr) {
          float p = sigd(xs[e]);
          if (p > pv) { pv = p; pi = q * 20 + 4 * k + e; }
        }
      }
    }
    #pragma unroll
    for (int xw = 1; xw <= 2; xw <<= 1) {
      float ov = __shfl_xor(pv, xw);
      int   oi = __shfl_xor(pi, xw);
      if (ov > pv || (ov == pv && oi < pi)) { pv = ov; pi = oi; }
    }
    pmax = pv; ci = pi;
  } else {
    pmax = sigd(m); ci = mi;
  }

  if (q == 0) {
    int lev, idx, nl; levinfo(g, lev, idx, nl);
    const float* ctrb;
    if      (lev == 0) ctrb = P.ctr0;
    else if (lev == 1) ctrb = P.ctr1;
    else if (lev == 2) ctrb = P.ctr2;
    else if (lev == 3) ctrb = P.ctr3;
    else               ctrb = P.ctr4;
    float tc = ctrb[(size_t)b * nl + idx];
    float csig = sigd(tc);
    float prod = pmax * csig;
    float s = (float)sqrt((double)prod);
    ((u16*)(P.ws + CLSI_OFF))[(size_t)b * TOTAL_G + g] = (u16)ci;
    unsigned hi = ~__float_as_uint(s);
    u64 key = ((u64)hi << 15) | (unsigned)g;
    if      (lev == 0) ((u64*)(P.ws + KEYS0_OFF))  [(size_t)b * 12800 + idx] = key;
    else if (lev == 1) ((u64*)(P.ws + KEYS1_OFF))  [(size_t)b * 3200  + idx] = key;
    else               ((u64*)(P.ws + KEYS234_OFF))[(size_t)b * 1088  + (g - 16000)] = key;
    // per-image histogram of valid keys' bits [40:29] (for the prefix boundary)
    if (hi < INVALID_HI)
      atomicAdd(&((u32*)(P.ws + HIST_OFF))[b * 4096 + (u32)((key >> 29) & 0xFFF)], 1u);
  }
}

__device__ __forceinline__ u64 loadkey(const Ptrs& P, int b, int u) {
  if (u < 12800) return ((const u64*)(P.ws + KEYS0_OFF))  [(size_t)b * 12800 + u];
  if (u < 16000) return ((const u64*)(P.ws + KEYS1_OFF))  [(size_t)b * 3200  + (u - 12800)];
  return               ((const u64*)(P.ws + KEYS234_OFF))[(size_t)b * 1088  + (u - 16000)];
}
// paired load; u even; segment boundaries (12800/16000) even so no crossing.
// u up to 18430 reads garbage within ws (guarded out by u < TOTAL_G later).
__device__ __forceinline__ ulonglong2 loadkey2(const Ptrs& P, int b, int u) {
  if (u < 12800) return *(const ulonglong2*)((const u64*)(P.ws + KEYS0_OFF)   + (size_t)b * 12800 + u);
  if (u < 16000) return *(const ulonglong2*)((const u64*)(P.ws + KEYS1_OFF)   + (size_t)b * 3200  + (u - 12800));
  return               *(const ulonglong2*)((const u64*)(P.ws + KEYS234_OFF) + (size_t)b * 1088  + (u - 16000));
}
__device__ __forceinline__ bool keep_pred(u64 k, int u, u64 T0, u64 T1) {
  bool valid = (u32)(k >> 15) < INVALID_HI;
  bool sel = (u < 12800) ? (k <= T0) : ((u < 16000) ? (k <= T1) : true);
  return valid && sel;
}

// ---------------- K2: boundary from global hist + vectorized compact (grid 16) ----------------
// Boundary semantics identical to R12: first 12-bit bin where cum >= 512 ->
// working set = valid keys < Boundary (a TRUE PREFIX, n512 < 512); if cum never
// reaches 512, Boundary = first invalid key (all valid keys). Exact fallback in
// k_reduce covers keeps beyond the prefix.
__global__ __launch_bounds__(1024) void k_prep(Ptrs P) {
  __shared__ u32 h[4096];
  __shared__ int wbase[144];
  __shared__ u64 sBoundary;
  __shared__ int sN5;
  int b = blockIdx.x;
  int tid = threadIdx.x, wid = tid >> 6, lane = tid & 63;
  char* ws = P.ws;

  const u32* gh = (const u32*)(ws + HIST_OFF) + (size_t)b * 4096;
  for (int i = tid; i < 4096; i += 1024) h[i] = gh[i];
  __syncthreads();

  // single-wave two-level cumsum -> first bin where cum >= 512
  if (wid == 0) {
    u32 ssum = 0;
    #pragma unroll 8
    for (int i = 0; i < 64; ++i) {
      int ii = (i + lane) & 63;
      ssum += h[(lane << 6) + ii];
    }
    u32 inc = ssum;
    for (int o = 1; o < 64; o <<= 1) { u32 v = __shfl_up(inc, o); if (lane >= o) inc += v; }
    u64 ball = __ballot(inc >= 512u);
    if (!ball) {
      if (lane == 0) sBoundary = ((u64)INVALID_HI << 15);   // all valid keys
    } else {
      int Wq = __ffsll(ball) - 1;
      u32 cumBefore = __shfl(inc - ssum, Wq);
      u32 v2 = h[(Wq << 6) + lane];
      u32 inc2 = v2;
      for (int o = 1; o < 64; o <<= 1) { u32 x = __shfl_up(inc2, o); if (lane >= o) inc2 += x; }
      u64 ball2 = __ballot(cumBefore + inc2 >= 512u);
      int l2 = __ffsll(ball2) - 1;
      if (lane == 0) {
        int d = (Wq << 6) + l2;
        sBoundary = (48ull << 41) | ((u64)d << 29);
      }
    }
  }
  __syncthreads();
  u64 Boundary = sBoundary;
  if (tid == 0) ((u64*)(ws + T512_OFF))[b] = Boundary - 1;

  // pass A: per-wave keep counts, 2 keys/thread (9 x 2048)
  for (int it = 0; it < 9; ++it) {
    int u = it * 2048 + tid * 2;
    ulonglong2 kk = loadkey2(P, b, u);
    bool k0 = (u     < TOTAL_G) && ((u32)(kk.x >> 15) < INVALID_HI) && (kk.x < Boundary);
    bool k1 = (u + 1 < TOTAL_G) && ((u32)(kk.y >> 15) < INVALID_HI) && (kk.y < Boundary);
    u64 b0 = __ballot(k0), b1 = __ballot(k1);
    if (lane == 0) wbase[it * 16 + wid] = __popcll(b0) + __popcll(b1);
  }
  __syncthreads();
  if (wid == 0) {
    int carry = 0;
    for (int base = 0; base < 144; base += 64) {
      int idx = base + lane;
      int v = (idx < 144) ? wbase[idx] : 0;
      int inc = v;
      for (int o = 1; o < 64; o <<= 1) { int x = __shfl_up(inc, o); if (lane >= o) inc += x; }
      if (idx < 144) wbase[idx] = inc - v + carry;
      carry += __shfl(inc, 63);
    }
    if (lane == 0) sN5 = carry;
  }
  __syncthreads();
  if (tid == 0) ((int*)(ws + NC_OFF))[16 + b] = sN5;

  // pass B: ordered scatter of the prefix set to global k512
  u64* k5 = k512_of(ws, b);
  for (int it = 0; it < 9; ++it) {
    int u = it * 2048 + tid * 2;
    ulonglong2 kk = loadkey2(P, b, u);
    bool k0 = (u     < TOTAL_G) && ((u32)(kk.x >> 15) < INVALID_HI) && (kk.x < Boundary);
    bool k1 = (u + 1 < TOTAL_G) && ((u32)(kk.y >> 15) < INVALID_HI) && (kk.y < Boundary);
    u64 b0 = __ballot(k0), b1 = __ballot(k1);
    u64 lm = (1ull << lane) - 1ull;
    int pos0 = wbase[it * 16 + wid] + __popcll(b0 & lm) + __popcll(b1 & lm);
    int pos1 = pos0 + (k0 ? 1 : 0);
    if (k0) k5[pos0] = kk.x;
    if (k1) k5[pos1] = kk.y;
  }
}

// ---------------- K3: scan-free decode + rank + rank-space mask (grid 4 x 16) ----------------
__global__ __launch_bounds__(1024) void k_mask(Ptrs P) {
  __shared__ u64 skey[512];
  __shared__ float4 sbox[512];
  __shared__ u16 srank[512];
  __shared__ u16 parts[1024];
  __shared__ u64 smaskR[4096];   // 32 KB, rank-space rows
  int qi = blockIdx.x, b = blockIdx.y;
  int tid = threadIdx.x;
  char* ws = P.ws;
  int n512 = ((int*)(ws + NC_OFF))[16 + b];
  const u64* k5 = k512_of(ws, b);

  if (tid < 512) {
    if (tid < n512) {
      u64 k = k5[tid];
      skey[tid] = k;
      sbox[tid] = decode_box(P, b, (int)(k & 0x7FFF));
    } else {
      skey[tid] = (ALLF - 511) + (u64)tid;   // distinct, > any real key
      sbox[tid] = make_float4(-1e30f, -1e30f, -1e30f, -1e30f);
    }
  }
  for (int i = tid; i < 512 * 8; i += 1024) smaskR[i] = 0ull;
  __syncthreads();

  // rank all 512 by key
  {
    int t2 = tid & 511, half = tid >> 9;
    u64 mykey = skey[t2];
    int jb = half << 8, cnt = 0;
    #pragma unroll 4
    for (int j = jb; j < jb + 256; ++j) cnt += (skey[j] < mykey) ? 1 : 0;
    parts[tid] = (u16)cnt;
  }
  __syncthreads();
  if (tid < 512) srank[tid] = (u16)(parts[tid] + parts[tid + 512]);
  __syncthreads();

  // suppression bits in rank space (rotated j-scan, conflict-free)
  int i = qi * 128 + (tid >> 3);
  int w = tid & 7;
  float4 bi = sbox[i];
  u64 ki = skey[i];
  int ri = srank[i];
  float ia = (bi.z - bi.x) * (bi.w - bi.y);
  #pragma unroll 8
  for (int bj = 0; bj < 64; ++bj) {
    int jj = (bj + w) & 63;
    int j = (w << 6) | jj;
    u64 kj = skey[j];
    if (ki < kj) {
      float4 bj4 = sbox[j];
      float ja  = (bj4.z - bj4.x) * (bj4.w - bj4.y);
      float ltx = fmaxf(bi.x, bj4.x), lty = fmaxf(bi.y, bj4.y);
      float rbx = fminf(bi.z, bj4.z), rby = fminf(bi.w, bj4.w);
      float wv = fmaxf(rbx - ltx, 0.0f), hv = fmaxf(rby - lty, 0.0f);
      float inter = wv * hv;
      float iou = inter / (ia + ja - inter);   // exact: integer-valued fp32
      if (iou > 0.6f) {
        int rj = srank[j];
        atomicOr(&smaskR[ri * 8 + (rj >> 6)], 1ull << (rj & 63));
      }
    }
  }
  __syncthreads();

  {
    int il = tid >> 3, ww = tid & 7;
    int ig = qi * 128 + il;
    if (ig < n512) {
      int r = srank[ig];
      msk_of(ws, b)[r * 8 + ww] = smaskR[r * 8 + ww];
      if (ww == 0) krank_of(ws, b)[r] = skey[ig];
    }
  }
}

// ---------------- 256-thread exact radix select (fallback only; no early exits) ----------------
__device__ u64 select256(const u64* keys, int n, int t0, u32* hist, u64* shP, int* shT) {
  u64 Pfx = 3; int t = t0;
  const int SS[4] = {33, 21, 9, 0};
  const int WW[4] = {12, 12, 12, 9};
  for (int p = 0; p < 4; ++p) {
    int s = SS[p], wb = WW[p];
    u32 dmask = (1u << wb) - 1u;
    for (int i = threadIdx.x; i < 4096; i += 256) hist[i] = 0;
    __syncthreads();
    for (int i = threadIdx.x; i < n; i += 256) {
      u64 k = keys[i];
      if ((k >> (s + wb)) == Pfx) atomicAdd(&hist[(u32)(k >> s) & dmask], 1u);
    }
    __syncthreads();
    if (threadIdx.x < 64) {
      int lane = threadIdx.x;
      u32 ssum = 0;
      for (int i = 0; i < 64; ++i) ssum += hist[(lane << 6) + ((i + lane) & 63)];
      u32 inc = ssum;
      for (int o = 1; o < 64; o <<= 1) { u32 v = __shfl_up(inc, o); if (lane >= o) inc += v; }
      u64 ball = __ballot(inc >= (u32)t);
      int Wq = __ffsll(ball) - 1;
      u32 cumBefore = __shfl(inc - ssum, Wq);
      u32 v2 = hist[(Wq << 6) + lane];
      u32 inc2 = v2;
      for (int o = 1; o < 64; o <<= 1) { u32 x = __shfl_up(inc2, o); if (lane >= o) inc2 += x; }
      u64 ball2 = __ballot(cumBefore + inc2 >= (u32)t);
      int l2 = __ffsll(ball2) - 1;
      u32 cumB2 = __shfl(cumBefore + inc2 - v2, l2);
      if (lane == 0) { *shP = (Pfx << wb) | (u32)((Wq << 6) + l2); *shT = t - (int)cumB2; }
    }
    __syncthreads();
    Pfx = *shP; t = *shT;
    __syncthreads();
  }
  return Pfx;   // final pass (s=0) yields the full 47-bit key
}

// ---------------- K4: greedy ffs walk + fallback + slotkey (grid 16, 256 thr) ----------------
__global__ __launch_bounds__(256) void k_reduce(Ptrs P) {
  __shared__ u64 smask[4096];       // 32 KB
  __shared__ u32 keeplist[100];     // ranks (walk phase only)
  __shared__ int keptS;
  __shared__ u64 liveC[267];        // fallback: live bits over gid space
  __shared__ union UF {
    u32 hist[4096];                 // 16 KB (fallback selects)
    struct { u64 pk[256]; int pc[256]; float4 fkb[100]; } F;
  } UF_;
  __shared__ u64 shP; __shared__ int shT;
  __shared__ u64 bk; __shared__ int bc2;

  int b = blockIdx.x;
  int tid = threadIdx.x;
  char* ws = P.ws;
  int n512 = ((int*)(ws + NC_OFF))[16 + b];
  const u64* kr = krank_of(ws, b);

  const u64* gmask = msk_of(ws, b);
  for (int t = tid; t < 4096; t += 256) smask[t] = gmask[t];
  __syncthreads();

  // single-wave barrier-free greedy walk over ranks [0, n512)
  if (tid < 64) {
    int lane = tid;
    u64 lw = 0;
    if (lane < 8) {
      int lo = lane << 6;
      int c = n512 - lo; if (c < 0) c = 0; if (c > 64) c = 64;
      lw = (c >= 64) ? ALLF : ((c > 0) ? ((1ull << c) - 1ull) : 0ull);
    }
    int kept = 0;
    while (kept < 100) {
      bool nz = (lane < 8) && (lw != 0ull);
      u64 bal = __ballot(nz);
      if (!bal) break;
      int W = __ffsll(bal) - 1;
      u64 wv = __shfl(lw, W);
      int bit = __ffsll(wv) - 1;
      int i = (W << 6) + bit;
      if (lane == 0) keeplist[kept] = (u32)i;
      kept++;
      if (lane == W) lw &= ~(1ull << bit);
      if (kept == 100) break;
      if (lane < 8) lw &= ~smask[i * 8 + lane];
    }
    if (lane == 0) keptS = kept;
  }
  __syncthreads();
  int kept = keptS;
  int keptW = kept;

  // fallback: keeps beyond the prefix (rare; exact)
  if (kept < 100) {
    u64 T0 = select256((const u64*)(ws + KEYS0_OFF) + (size_t)b * 12800, 12800, 1000,
                       UF_.hist, &shP, &shT);
    u64 T1 = select256((const u64*)(ws + KEYS1_OFF) + (size_t)b * 3200, 3200, 1000,
                       UF_.hist, &shP, &shT);
    u64 T512 = ((u64*)(ws + T512_OFF))[b];
    for (int w = tid; w < 267; w += 256) {
      int lo = w << 6;
      u64 m = 0;
      for (int e = 0; e < 64; ++e) {
        int u = lo + e;
        if (u < TOTAL_G) {
          u64 k = loadkey(P, b, u);
          if (keep_pred(k, u, T0, T1) && k > T512) m |= (1ull << e);
        }
      }
      liveC[w] = m;
    }
    if (tid < kept) UF_.F.fkb[tid] = decode_box(P, b, (int)(kr[keeplist[tid]] & 0x7FFF));
    __syncthreads();

    // seed suppression from already-kept items
    for (int k2 = 0; k2 < kept; ++k2) {
      float4 bi = UF_.F.fkb[k2];
      float ia = (bi.z - bi.x) * (bi.w - bi.y);
      for (int u = tid; u < TOTAL_G; u += 256) {
        if (!((liveC[u >> 6] >> (u & 63)) & 1ull)) continue;
        float4 bj4 = decode_box(P, b, u);
        float ja  = (bj4.z - bj4.x) * (bj4.w - bj4.y);
        float ltx = fmaxf(bi.x, bj4.x), lty = fmaxf(bi.y, bj4.y);
        float rbx = fminf(bi.z, bj4.z), rby = fminf(bi.w, bj4.w);
        float wv = fmaxf(rbx - ltx, 0.0f), hv = fmaxf(rby - lty, 0.0f);
        float inter = wv * hv;
        float iou = inter / (ia + ja - inter);
        if (iou > 0.6f) atomicAnd(&liveC[u >> 6], ~(1ull << (u & 63)));
      }
    }
    __syncthreads();

    // selection-by-min-key loop
    while (kept < 100) {
      u64 mymin = ALLF; int myc = -1;
      for (int u = tid; u < TOTAL_G; u += 256) {
        if (!((liveC[u >> 6] >> (u & 63)) & 1ull)) continue;
        u64 k = loadkey(P, b, u);
        if (k < mymin) { mymin = k; myc = u; }
      }
      UF_.F.pk[tid] = mymin; UF_.F.pc[tid] = myc;
      __syncthreads();
      if (tid < 64) {
        u64 m = UF_.F.pk[tid]; int c0 = UF_.F.pc[tid];
        #pragma unroll
        for (int o = 64; o < 256; o += 64)
          if (UF_.F.pk[tid + o] < m) { m = UF_.F.pk[tid + o]; c0 = UF_.F.pc[tid + o]; }
        for (int o = 32; o > 0; o >>= 1) {
          u64 om = __shfl_down(m, o); int oc = __shfl_down(c0, o);
          if (om < m) { m = om; c0 = oc; }
        }
        if (tid == 0) { bk = m; bc2 = c0; }
      }
      __syncthreads();
      if (bk == ALLF) break;
      int cs = bc2;
      if (tid == 0) {
        slotkey_of(ws, b)[kept] = bk;     // fallback keeps write slotkey directly
        atomicAnd(&liveC[cs >> 6], ~(1ull << (cs & 63)));
      }
      __syncthreads();
      kept++;
      if (kept == 100) break;
      float4 bi = decode_box(P, b, cs);
      float ia = (bi.z - bi.x) * (bi.w - bi.y);
      for (int u = tid; u < TOTAL_G; u += 256) {
        if (!((liveC[u >> 6] >> (u & 63)) & 1ull)) continue;
        float4 bj4 = decode_box(P, b, u);
        float ja  = (bj4.z - bj4.x) * (bj4.w - bj4.y);
        float ltx = fmaxf(bi.x, bj4.x), lty = fmaxf(bi.y, bj4.y);
        float rbx = fminf(bi.z, bj4.z), rby = fminf(bi.w, bj4.w);
        float wv = fmaxf(rbx - ltx, 0.0f), hv = fmaxf(rby - lty, 0.0f);
        float inter = wv * hv;
        float iou = inter / (ia + ja - inter);
        if (iou > 0.6f) atomicAnd(&liveC[u >> 6], ~(1ull << (u & 63)));
      }
      __syncthreads();
    }
  }

  // resolve slot keys: walk entries via kr; fallback entries already written; rest = ALLF
  if (tid < 100) {
    if (tid < keptW)      slotkey_of(ws, b)[tid] = kr[keeplist[tid]];
    else if (tid >= kept) slotkey_of(ws, b)[tid] = ALLF;
  }
}

// ---------------- K5: parallel outputs (grid 16 x 10, 256 thr) ----------------
__global__ __launch_bounds__(256) void k_out(Ptrs P, float* out) {
  int b = blockIdx.x, part = blockIdx.y;   // 10 slots per block
  int s0 = part * 10;
  int tid = threadIdx.x;
  const u64* skl = slotkey_of(P.ws, b);

  if (tid < 10) {
    int s = s0 + tid;
    u64 key = skl[s];
    float os = -1.0f, oc = -1.0f;
    float4 bx = make_float4(-1.0f, -1.0f, -1.0f, -1.0f);
    if (key != ALLF) {
      int gid = (int)(key & 0x7FFF);
      os = __uint_as_float(~(u32)(key >> 15));
      oc = (float)((u16*)(P.ws + CLSI_OFF))[(size_t)b * TOTAL_G + gid];
      bx = decode_box(P, b, gid);
    }
    out[b * 100 + s] = os;
    out[1600 + b * 100 + s] = oc;
    *(float4*)(out + 3200 + (size_t)(b * 100 + s) * 4) = bx;
  }

  for (int t = tid; t < 800; t += 256) {
    int sl = t / 80, k = t - sl * 80;
    int s = s0 + sl;
    u64 key = skl[s];
    float val = -1.0f;
    if (key != ALLF) {
      int gid = (int)(key & 0x7FFF);
      int lev, idx, nl; levinfo(gid, lev, idx, nl);
      const float* cp;
      if      (lev == 0) cp = P.cls0;
      else if (lev == 1) cp = P.cls1;
      else if (lev == 2) cp = P.cls2;
      else if (lev == 3) cp = P.cls3;
      else               cp = P.cls4;
      val = sigd(cp[(size_t)(b * nl + idx) * 80 + k]);
    }
    out[9600 + (size_t)(b * 100 + s) * 80 + k] = val;
  }
}

extern "C" void kernel_launch(void* const* d_in, const int* in_sizes, int n_in,
                              void* d_out, int out_size, void* d_ws, size_t ws_size,
                              hipStream_t stream) {
  (void)in_sizes; (void)n_in; (void)out_size; (void)ws_size;
  Ptrs P;
  P.cls0 = (const float*)d_in[0];  P.reg0 = (const float*)d_in[1];
  P.ctr0 = (const float*)d_in[2];  P.pos0 = (const float*)d_in[3];
  P.cls1 = (const float*)d_in[4];  P.reg1 = (const float*)d_in[5];
  P.ctr1 = (const float*)d_in[6];  P.pos1 = (const float*)d_in[7];
  P.cls2 = (const float*)d_in[8];  P.reg2 = (const float*)d_in[9];
  P.ctr2 = (const float*)d_in[10]; P.pos2 = (const float*)d_in[11];
  P.cls3 = (const float*)d_in[12]; P.reg3 = (const float*)d_in[13];
  P.ctr3 = (const float*)d_in[14]; P.pos3 = (const float*)d_in[15];
  P.cls4 = (const float*)d_in[16]; P.reg4 = (const float*)d_in[17];
  P.ctr4 = (const float*)d_in[18]; P.pos4 = (const float*)d_in[19];
  P.ws = (char*)d_ws;

  // zero the per-image boundary histograms (k_score accumulates into them)
  (void)hipMemsetAsync((char*)d_ws + HIST_OFF, 0, 16 * 4096 * 4, stream);

  k_score<<<dim3(267, 16), 256, 0, stream>>>(P);
  k_prep<<<16, 1024, 0, stream>>>(P);
  k_mask<<<dim3(4, 16), 1024, 0, stream>>>(P);
  k_reduce<<<16, 256, 0, stream>>>(P);
  k_out<<<dim3(16, 10), 256, 0, stream>>>(P, (float*)d_out);
}

// Round 14
// 96.062 us; speedup vs baseline: 1.6174x; 1.6174x over previous
//
#include <hip/hip_runtime.h>
#include <math.h>

#define TOTAL_G 17064
#define BATCHN  16
#define ALLF    0xFFFFFFFFFFFFFFFFull
// valid <=> score > 0.01f <=> scorebits > 0x3C23D70A <=> (key>>15) < 0xC3DC28F5
#define INVALID_HI 0xC3DC28F5u

typedef unsigned long long u64;
typedef unsigned int u32;
typedef unsigned short u16;

// ---- ws layout (bytes), total 3,402,112 ----
#define KEYS0_OFF   0          // u64[16][12800]  1,638,400
#define KEYS1_OFF   1638400    // u64[16][3200]     409,600
#define KEYS234_OFF 2048000    // u64[16][1088]     139,264
#define CLSI_OFF    2187264    // u16[16][17064]    546,048
#define NC_OFF      2733312    // int[32]: [16..31]=n512
#define T512_OFF    2733824    // u64[16]  (= Boundary-1; fallback predicate k > T512)
#define KR_OFF      2733952    // u64[16][512]       65,536
#define MSK_OFF     2799488    // u64[16][512*8]    524,288
#define SLOTK_OFF   3323776    // u64[16][100]       12,800
#define K512_OFF    3336576    // u64[16][512]       65,536

struct Ptrs {
  const float *cls0,*cls1,*cls2,*cls3,*cls4;
  const float *reg0,*reg1,*reg2,*reg3,*reg4;
  const float *ctr0,*ctr1,*ctr2,*ctr3,*ctr4;
  const float *pos0,*pos1,*pos2,*pos3,*pos4;
  char *ws;
};

__device__ __forceinline__ float sigd(float x) {
  return (float)(1.0 / (1.0 + exp(-(double)x)));
}
__device__ __forceinline__ float dexp(float x) {
  return (float)exp((double)x);
}
__device__ __forceinline__ void levinfo(int gid, int& lev, int& idx, int& nl) {
  if      (gid < 12800) { lev=0; idx=gid;        nl=12800; }
  else if (gid < 16000) { lev=1; idx=gid-12800;  nl=3200;  }
  else if (gid < 16800) { lev=2; idx=gid-16000;  nl=800;   }
  else if (gid < 17008) { lev=3; idx=gid-16800;  nl=208;   }
  else                  { lev=4; idx=gid-17008;  nl=56;    }
}

__device__ __forceinline__ u64* krank_of(char* ws, int b) {
  return (u64*)(ws + KR_OFF + (size_t)b * 4096);
}
__device__ __forceinline__ u64* msk_of(char* ws, int b) {
  return (u64*)(ws + MSK_OFF + (size_t)b * 32768);
}
__device__ __forceinline__ u64* slotkey_of(char* ws, int b) {
  return (u64*)(ws + SLOTK_OFF + (size_t)b * 800);
}
__device__ __forceinline__ u64* k512_of(char* ws, int b) {
  return (u64*)(ws + K512_OFF + (size_t)b * 4096);
}

// exact box decode (identical everywhere -> deterministic)
__device__ __forceinline__ float4 decode_box(const Ptrs& P, int b, int gid) {
  int lev, idx, nl; levinfo(gid, lev, idx, nl);
  const float *rp, *pp;
  if      (lev == 0) { rp = P.reg0; pp = P.pos0; }
  else if (lev == 1) { rp = P.reg1; pp = P.pos1; }
  else if (lev == 2) { rp = P.reg2; pp = P.pos2; }
  else if (lev == 3) { rp = P.reg3; pp = P.pos3; }
  else               { rp = P.reg4; pp = P.pos4; }
  float4 rv = *(const float4*)(rp + (size_t)(b * nl + idx) * 4);
  float2 pv = *(const float2*)(pp + (size_t)(b * nl + idx) * 2);
  float e0 = dexp(rv.x), e1 = dexp(rv.y), e2 = dexp(rv.z), e3 = dexp(rv.w);
  float x1 = truncf(pv.x - e0), y1 = truncf(pv.y - e1);
  float x2 = truncf(pv.x + e2), y2 = truncf(pv.y + e3);
  x1 = fmaxf(x1, 0.0f); y1 = fmaxf(y1, 0.0f);
  x2 = fminf(x2, 1023.0f); y2 = fminf(y2, 799.0f);
  return make_float4(x1, y1, x2, y2);
}

// ---------------- K1: LDS-staged, 4-threads-per-position score / argmax / key ----------------
// (R12 version — NO global histogram atomics; that was R13's regression)
__global__ __launch_bounds__(256) void k_score(Ptrs P) {
  __shared__ float4 sk4[64 * 20];   // 64 positions x 320 B = 20 KB
  int b = blockIdx.y;
  int tid = threadIdx.x;
  int p0 = blockIdx.x * 64;

  #pragma unroll
  for (int it = 0; it < 5; ++it) {
    int t4 = it * 256 + tid;
    int g = p0 + t4 / 20;
    if (g < TOTAL_G) {
      int sub = t4 - (t4 / 20) * 20;
      int lev, idx, nl; levinfo(g, lev, idx, nl);
      const float* clsb;
      if      (lev == 0) clsb = P.cls0;
      else if (lev == 1) clsb = P.cls1;
      else if (lev == 2) clsb = P.cls2;
      else if (lev == 3) clsb = P.cls3;
      else               clsb = P.cls4;
      sk4[t4] = ((const float4*)(clsb + (size_t)(b * nl + idx) * 80))[sub];
    }
  }
  __syncthreads();

  int lp = tid >> 2, q = tid & 3;
  int g = p0 + lp;
  if (g >= TOTAL_G) return;

  const float4* my4 = &sk4[lp * 20 + q * 5];
  float m = -INFINITY, m2 = -INFINITY; int mi = 0;
  #pragma unroll
  for (int k = 0; k < 5; ++k) {
    float4 v = my4[k];
    int base = q * 20 + 4 * k;
    if (v.x > m) { m2 = m; m = v.x; mi = base+0; } else if (v.x > m2) m2 = v.x;
    if (v.y > m) { m2 = m; m = v.y; mi = base+1; } else if (v.y > m2) m2 = v.y;
    if (v.z > m) { m2 = m; m = v.z; mi = base+2; } else if (v.z > m2) m2 = v.z;
    if (v.w > m) { m2 = m; m = v.w; mi = base+3; } else if (v.w > m2) m2 = v.w;
  }
  #pragma unroll
  for (int xw = 1; xw <= 2; xw <<= 1) {
    float om  = __shfl_xor(m,  xw);
    float om2 = __shfl_xor(m2, xw);
    int   omi = __shfl_xor(mi, xw);
    bool take = (om > m) || (om == m && omi < mi);
    float lm  = take ? m : om;
    float wm2 = take ? om2 : m2;
    if (take) { m = om; mi = omi; }
    m2 = fmaxf(lm, wm2);
  }

  float thr = fminf(m - 1e-3f, 9.0f);
  float pmax; int ci;
  if (m2 >= thr) {
    // rare exact path: per-element sigmoid argmax among candidates >= thr
    float pv = -1.0f; int pi = 0x7fffffff;
    #pragma unroll 1
    for (int k = 0; k < 5; ++k) {
      float4 v = my4[k];
      float xs[4] = {v.x, v.y, v.z, v.w};
      #pragma unroll
      for (int e = 0; e < 4; ++e) {
        if (xs[e] >= thr) {
          float p = sigd(xs[e]);
          if (p > pv) { pv = p; pi = q * 20 + 4 * k + e; }
        }
      }
    }
    #pragma unroll
    for (int xw = 1; xw <= 2; xw <<= 1) {
      float ov = __shfl_xor(pv, xw);
      int   oi = __shfl_xor(pi, xw);
      if (ov > pv || (ov == pv && oi < pi)) { pv = ov; pi = oi; }
    }
    pmax = pv; ci = pi;
  } else {
    pmax = sigd(m); ci = mi;
  }

  if (q == 0) {
    int lev, idx, nl; levinfo(g, lev, idx, nl);
    const float* ctrb;
    if      (lev == 0) ctrb = P.ctr0;
    else if (lev == 1) ctrb = P.ctr1;
    else if (lev == 2) ctrb = P.ctr2;
    else if (lev == 3) ctrb = P.ctr3;
    else               ctrb = P.ctr4;
    float tc = ctrb[(size_t)b * nl + idx];
    float csig = sigd(tc);
    float prod = pmax * csig;
    float s = (float)sqrt((double)prod);
    ((u16*)(P.ws + CLSI_OFF))[(size_t)b * TOTAL_G + g] = (u16)ci;
    unsigned hi = ~__float_as_uint(s);
    u64 key = ((u64)hi << 15) | (unsigned)g;
    if      (lev == 0) ((u64*)(P.ws + KEYS0_OFF))  [(size_t)b * 12800 + idx] = key;
    else if (lev == 1) ((u64*)(P.ws + KEYS1_OFF))  [(size_t)b * 3200  + idx] = key;
    else               ((u64*)(P.ws + KEYS234_OFF))[(size_t)b * 1088  + (g - 16000)] = key;
  }
}

__device__ __forceinline__ u64 loadkey(const Ptrs& P, int b, int u) {
  if (u < 12800) return ((const u64*)(P.ws + KEYS0_OFF))  [(size_t)b * 12800 + u];
  if (u < 16000) return ((const u64*)(P.ws + KEYS1_OFF))  [(size_t)b * 3200  + (u - 12800)];
  return               ((const u64*)(P.ws + KEYS234_OFF))[(size_t)b * 1088  + (u - 16000)];
}
// paired load; u even; segment boundaries (12800/16000) even so no crossing.
// u up to 18430 reads garbage within ws (guarded out by u < TOTAL_G checks).
__device__ __forceinline__ ulonglong2 loadkey2(const Ptrs& P, int b, int u) {
  if (u < 12800) return *(const ulonglong2*)((const u64*)(P.ws + KEYS0_OFF)   + (size_t)b * 12800 + u);
  if (u < 16000) return *(const ulonglong2*)((const u64*)(P.ws + KEYS1_OFF)   + (size_t)b * 3200  + (u - 12800));
  return               *(const ulonglong2*)((const u64*)(P.ws + KEYS234_OFF) + (size_t)b * 1088  + (u - 16000));
}
__device__ __forceinline__ bool keep_pred(u64 k, int u, u64 T0, u64 T1) {
  bool valid = (u32)(k >> 15) < INVALID_HI;
  bool sel = (u < 12800) ? (k <= T0) : ((u < 16000) ? (k <= T1) : true);
  return valid && sel;
}

// ---------------- K2: LDS histogram + boundary + vectorized compact (grid 16) ----------------
// Boundary semantics identical to R12: first 12-bit bin (key bits [40:29]) where
// cum >= 512 -> working set = valid keys < Boundary (TRUE PREFIX, n512 < 512);
// if cum never reaches 512, Boundary = first invalid key. Exact fallback in
// k_reduce covers keeps beyond the prefix.
__global__ __launch_bounds__(1024) void k_prep(Ptrs P) {
  __shared__ u32 h[4][4096];    // 64 KB, 4 replicas vs clustered-score contention
  __shared__ int wbase[144];
  __shared__ u64 sBoundary;
  __shared__ int sN5;
  int b = blockIdx.x;
  int tid = threadIdx.x, wid = tid >> 6, lane = tid & 63;
  int rep = wid & 3;
  char* ws = P.ws;

  // phase 1: histogram scan (2 keys/thread)
  for (int i = tid; i < 4 * 4096; i += 1024) (&h[0][0])[i] = 0;
  __syncthreads();
  for (int it = 0; it < 9; ++it) {
    int u = it * 2048 + tid * 2;
    if (u >= TOTAL_G) break;
    ulonglong2 kk = loadkey2(P, b, u);
    if ((u32)(kk.x >> 15) < INVALID_HI)
      atomicAdd(&h[rep][(u32)(kk.x >> 29) & 0xFFF], 1u);
    if (u + 1 < TOTAL_G && (u32)(kk.y >> 15) < INVALID_HI)
      atomicAdd(&h[rep][(u32)(kk.y >> 29) & 0xFFF], 1u);
  }
  __syncthreads();
  for (int i = tid; i < 4096; i += 1024)
    h[0][i] = h[0][i] + h[1][i] + h[2][i] + h[3][i];
  __syncthreads();

  // phase 2: single-wave two-level cumsum -> first bin where cum >= 512
  if (wid == 0) {
    u32 ssum = 0;
    #pragma unroll 8
    for (int i = 0; i < 64; ++i) {
      int ii = (i + lane) & 63;
      ssum += h[0][(lane << 6) + ii];
    }
    u32 inc = ssum;
    for (int o = 1; o < 64; o <<= 1) { u32 v = __shfl_up(inc, o); if (lane >= o) inc += v; }
    u64 ball = __ballot(inc >= 512u);
    if (!ball) {
      if (lane == 0) sBoundary = ((u64)INVALID_HI << 15);   // all valid keys
    } else {
      int Wq = __ffsll(ball) - 1;
      u32 cumBefore = __shfl(inc - ssum, Wq);
      u32 v2 = h[0][(Wq << 6) + lane];
      u32 inc2 = v2;
      for (int o = 1; o < 64; o <<= 1) { u32 x = __shfl_up(inc2, o); if (lane >= o) inc2 += x; }
      u64 ball2 = __ballot(cumBefore + inc2 >= 512u);
      int l2 = __ffsll(ball2) - 1;
      if (lane == 0) {
        int d = (Wq << 6) + l2;
        sBoundary = (48ull << 41) | ((u64)d << 29);
      }
    }
  }
  __syncthreads();
  u64 Boundary = sBoundary;
  if (tid == 0) ((u64*)(ws + T512_OFF))[b] = Boundary - 1;

  // phase 3: per-wave keep counts, 2 keys/thread
  for (int it = 0; it < 9; ++it) {
    int u = it * 2048 + tid * 2;
    ulonglong2 kk = loadkey2(P, b, u);
    bool k0 = (u     < TOTAL_G) && ((u32)(kk.x >> 15) < INVALID_HI) && (kk.x < Boundary);
    bool k1 = (u + 1 < TOTAL_G) && ((u32)(kk.y >> 15) < INVALID_HI) && (kk.y < Boundary);
    u64 b0 = __ballot(k0), b1 = __ballot(k1);
    if (lane == 0) wbase[it * 16 + wid] = __popcll(b0) + __popcll(b1);
  }
  __syncthreads();
  if (wid == 0) {
    int carry = 0;
    for (int base = 0; base < 144; base += 64) {
      int idx = base + lane;
      int v = (idx < 144) ? wbase[idx] : 0;
      int inc = v;
      for (int o = 1; o < 64; o <<= 1) { int x = __shfl_up(inc, o); if (lane >= o) inc += x; }
      if (idx < 144) wbase[idx] = inc - v + carry;
      carry += __shfl(inc, 63);
    }
    if (lane == 0) sN5 = carry;
  }
  __syncthreads();
  if (tid == 0) ((int*)(ws + NC_OFF))[16 + b] = sN5;

  // phase 4: ordered scatter of the prefix set to global k512
  u64* k5 = k512_of(ws, b);
  for (int it = 0; it < 9; ++it) {
    int u = it * 2048 + tid * 2;
    ulonglong2 kk = loadkey2(P, b, u);
    bool k0 = (u     < TOTAL_G) && ((u32)(kk.x >> 15) < INVALID_HI) && (kk.x < Boundary);
    bool k1 = (u + 1 < TOTAL_G) && ((u32)(kk.y >> 15) < INVALID_HI) && (kk.y < Boundary);
    u64 b0 = __ballot(k0), b1 = __ballot(k1);
    u64 lm = (1ull << lane) - 1ull;
    int pos0 = wbase[it * 16 + wid] + __popcll(b0 & lm) + __popcll(b1 & lm);
    int pos1 = pos0 + (k0 ? 1 : 0);
    if (k0) k5[pos0] = kk.x;
    if (k1) k5[pos1] = kk.y;
  }
}

// ---------------- K3: scan-free decode + rank + rank-space mask (grid 4 x 16) ----------------
__global__ __launch_bounds__(1024) void k_mask(Ptrs P) {
  __shared__ u64 skey[512];
  __shared__ float4 sbox[512];
  __shared__ u16 srank[512];
  __shared__ u16 parts[1024];
  __shared__ u64 smaskR[4096];   // 32 KB, rank-space rows
  int qi = blockIdx.x, b = blockIdx.y;
  int tid = threadIdx.x;
  char* ws = P.ws;
  int n512 = ((int*)(ws + NC_OFF))[16 + b];
  const u64* k5 = k512_of(ws, b);

  if (tid < 512) {
    if (tid < n512) {
      u64 k = k5[tid];
      skey[tid] = k;
      sbox[tid] = decode_box(P, b, (int)(k & 0x7FFF));
    } else {
      skey[tid] = (ALLF - 511) + (u64)tid;   // distinct, > any real key
      sbox[tid] = make_float4(-1e30f, -1e30f, -1e30f, -1e30f);
    }
  }
  for (int i = tid; i < 512 * 8; i += 1024) smaskR[i] = 0ull;
  __syncthreads();

  // rank all 512 by key
  {
    int t2 = tid & 511, half = tid >> 9;
    u64 mykey = skey[t2];
    int jb = half << 8, cnt = 0;
    #pragma unroll 4
    for (int j = jb; j < jb + 256; ++j) cnt += (skey[j] < mykey) ? 1 : 0;
    parts[tid] = (u16)cnt;
  }
  __syncthreads();
  if (tid < 512) srank[tid] = (u16)(parts[tid] + parts[tid + 512]);
  __syncthreads();

  // suppression bits in rank space (rotated j-scan, conflict-free)
  int i = qi * 128 + (tid >> 3);
  int w = tid & 7;
  float4 bi = sbox[i];
  u64 ki = skey[i];
  int ri = srank[i];
  float ia = (bi.z - bi.x) * (bi.w - bi.y);
  #pragma unroll 8
  for (int bj = 0; bj < 64; ++bj) {
    int jj = (bj + w) & 63;
    int j = (w << 6) | jj;
    u64 kj = skey[j];
    if (ki < kj) {
      float4 bj4 = sbox[j];
      float ja  = (bj4.z - bj4.x) * (bj4.w - bj4.y);
      float ltx = fmaxf(bi.x, bj4.x), lty = fmaxf(bi.y, bj4.y);
      float rbx = fminf(bi.z, bj4.z), rby = fminf(bi.w, bj4.w);
      float wv = fmaxf(rbx - ltx, 0.0f), hv = fmaxf(rby - lty, 0.0f);
      float inter = wv * hv;
      float iou = inter / (ia + ja - inter);   // exact: integer-valued fp32
      if (iou > 0.6f) {
        int rj = srank[j];
        atomicOr(&smaskR[ri * 8 + (rj >> 6)], 1ull << (rj & 63));
      }
    }
  }
  __syncthreads();

  {
    int il = tid >> 3, ww = tid & 7;
    int ig = qi * 128 + il;
    if (ig < n512) {
      int r = srank[ig];
      msk_of(ws, b)[r * 8 + ww] = smaskR[r * 8 + ww];
      if (ww == 0) krank_of(ws, b)[r] = skey[ig];
    }
  }
}

// ---------------- 256-thread exact radix select (fallback only; no early exits) ----------------
__device__ u64 select256(const u64* keys, int n, int t0, u32* hist, u64* shP, int* shT) {
  u64 Pfx = 3; int t = t0;
  const int SS[4] = {33, 21, 9, 0};
  const int WW[4] = {12, 12, 12, 9};
  for (int p = 0; p < 4; ++p) {
    int s = SS[p], wb = WW[p];
    u32 dmask = (1u << wb) - 1u;
    for (int i = threadIdx.x; i < 4096; i += 256) hist[i] = 0;
    __syncthreads();
    for (int i = threadIdx.x; i < n; i += 256) {
      u64 k = keys[i];
      if ((k >> (s + wb)) == Pfx) atomicAdd(&hist[(u32)(k >> s) & dmask], 1u);
    }
    __syncthreads();
    if (threadIdx.x < 64) {
      int lane = threadIdx.x;
      u32 ssum = 0;
      for (int i = 0; i < 64; ++i) ssum += hist[(lane << 6) + ((i + lane) & 63)];
      u32 inc = ssum;
      for (int o = 1; o < 64; o <<= 1) { u32 v = __shfl_up(inc, o); if (lane >= o) inc += v; }
      u64 ball = __ballot(inc >= (u32)t);
      int Wq = __ffsll(ball) - 1;
      u32 cumBefore = __shfl(inc - ssum, Wq);
      u32 v2 = hist[(Wq << 6) + lane];
      u32 inc2 = v2;
      for (int o = 1; o < 64; o <<= 1) { u32 x = __shfl_up(inc2, o); if (lane >= o) inc2 += x; }
      u64 ball2 = __ballot(cumBefore + inc2 >= (u32)t);
      int l2 = __ffsll(ball2) - 1;
      u32 cumB2 = __shfl(cumBefore + inc2 - v2, l2);
      if (lane == 0) { *shP = (Pfx << wb) | (u32)((Wq << 6) + l2); *shT = t - (int)cumB2; }
    }
    __syncthreads();
    Pfx = *shP; t = *shT;
    __syncthreads();
  }
  return Pfx;   // final pass (s=0) yields the full 47-bit key
}

// ---------------- K4: greedy ffs walk + fallback + slotkey (grid 16, 256 thr) ----------------
__global__ __launch_bounds__(256) void k_reduce(Ptrs P) {
  __shared__ u64 smask[4096];       // 32 KB
  __shared__ u32 keeplist[100];     // ranks (walk phase only)
  __shared__ int keptS;
  __shared__ u64 liveC[267];        // fallback: live bits over gid space
  __shared__ union UF {
    u32 hist[4096];                 // 16 KB (fallback selects)
    struct { u64 pk[256]; int pc[256]; float4 fkb[100]; } F;
  } UF_;
  __shared__ u64 shP; __shared__ int shT;
  __shared__ u64 bk; __shared__ int bc2;

  int b = blockIdx.x;
  int tid = threadIdx.x;
  char* ws = P.ws;
  int n512 = ((int*)(ws + NC_OFF))[16 + b];
  const u64* kr = krank_of(ws, b);

  const u64* gmask = msk_of(ws, b);
  for (int t = tid; t < 4096; t += 256) smask[t] = gmask[t];
  __syncthreads();

  // single-wave barrier-free greedy walk over ranks [0, n512)
  if (tid < 64) {
    int lane = tid;
    u64 lw = 0;
    if (lane < 8) {
      int lo = lane << 6;
      int c = n512 - lo; if (c < 0) c = 0; if (c > 64) c = 64;
      lw = (c >= 64) ? ALLF : ((c > 0) ? ((1ull << c) - 1ull) : 0ull);
    }
    int kept = 0;
    while (kept < 100) {
      bool nz = (lane < 8) && (lw != 0ull);
      u64 bal = __ballot(nz);
      if (!bal) break;
      int W = __ffsll(bal) - 1;
      u64 wv = __shfl(lw, W);
      int bit = __ffsll(wv) - 1;
      int i = (W << 6) + bit;
      if (lane == 0) keeplist[kept] = (u32)i;
      kept++;
      if (lane == W) lw &= ~(1ull << bit);
      if (kept == 100) break;
      if (lane < 8) lw &= ~smask[i * 8 + lane];
    }
    if (lane == 0) keptS = kept;
  }
  __syncthreads();
  int kept = keptS;
  int keptW = kept;

  // fallback: keeps beyond the prefix (rare; exact)
  if (kept < 100) {
    u64 T0 = select256((const u64*)(ws + KEYS0_OFF) + (size_t)b * 12800, 12800, 1000,
                       UF_.hist, &shP, &shT);
    u64 T1 = select256((const u64*)(ws + KEYS1_OFF) + (size_t)b * 3200, 3200, 1000,
                       UF_.hist, &shP, &shT);
    u64 T512 = ((u64*)(ws + T512_OFF))[b];
    for (int w = tid; w < 267; w += 256) {
      int lo = w << 6;
      u64 m = 0;
      for (int e = 0; e < 64; ++e) {
        int u = lo + e;
        if (u < TOTAL_G) {
          u64 k = loadkey(P, b, u);
          if (keep_pred(k, u, T0, T1) && k > T512) m |= (1ull << e);
        }
      }
      liveC[w] = m;
    }
    if (tid < kept) UF_.F.fkb[tid] = decode_box(P, b, (int)(kr[keeplist[tid]] & 0x7FFF));
    __syncthreads();

    // seed suppression from already-kept items
    for (int k2 = 0; k2 < kept; ++k2) {
      float4 bi = UF_.F.fkb[k2];
      float ia = (bi.z - bi.x) * (bi.w - bi.y);
      for (int u = tid; u < TOTAL_G; u += 256) {
        if (!((liveC[u >> 6] >> (u & 63)) & 1ull)) continue;
        float4 bj4 = decode_box(P, b, u);
        float ja  = (bj4.z - bj4.x) * (bj4.w - bj4.y);
        float ltx = fmaxf(bi.x, bj4.x), lty = fmaxf(bi.y, bj4.y);
        float rbx = fminf(bi.z, bj4.z), rby = fminf(bi.w, bj4.w);
        float wv = fmaxf(rbx - ltx, 0.0f), hv = fmaxf(rby - lty, 0.0f);
        float inter = wv * hv;
        float iou = inter / (ia + ja - inter);
        if (iou > 0.6f) atomicAnd(&liveC[u >> 6], ~(1ull << (u & 63)));
      }
    }
    __syncthreads();

    // selection-by-min-key loop
    while (kept < 100) {
      u64 mymin = ALLF; int myc = -1;
      for (int u = tid; u < TOTAL_G; u += 256) {
        if (!((liveC[u >> 6] >> (u & 63)) & 1ull)) continue;
        u64 k = loadkey(P, b, u);
        if (k < mymin) { mymin = k; myc = u; }
      }
      UF_.F.pk[tid] = mymin; UF_.F.pc[tid] = myc;
      __syncthreads();
      if (tid < 64) {
        u64 m = UF_.F.pk[tid]; int c0 = UF_.F.pc[tid];
        #pragma unroll
        for (int o = 64; o < 256; o += 64)
          if (UF_.F.pk[tid + o] < m) { m = UF_.F.pk[tid + o]; c0 = UF_.F.pc[tid + o]; }
        for (int o = 32; o > 0; o >>= 1) {
          u64 om = __shfl_down(m, o); int oc = __shfl_down(c0, o);
          if (om < m) { m = om; c0 = oc; }
        }
        if (tid == 0) { bk = m; bc2 = c0; }
      }
      __syncthreads();
      if (bk == ALLF) break;
      int cs = bc2;
      if (tid == 0) {
        slotkey_of(ws, b)[kept] = bk;     // fallback keeps write slotkey directly
        atomicAnd(&liveC[cs >> 6], ~(1ull << (cs & 63)));
      }
      __syncthreads();
      kept++;
      if (kept == 100) break;
      float4 bi = decode_box(P, b, cs);
      float ia = (bi.z - bi.x) * (bi.w - bi.y);
      for (int u = tid; u < TOTAL_G; u += 256) {
        if (!((liveC[u >> 6] >> (u & 63)) & 1ull)) continue;
        float4 bj4 = decode_box(P, b, u);
        float ja  = (bj4.z - bj4.x) * (bj4.w - bj4.y);
        float ltx = fmaxf(bi.x, bj4.x), lty = fmaxf(bi.y, bj4.y);
        float rbx = fminf(bi.z, bj4.z), rby = fminf(bi.w, bj4.w);
        float wv = fmaxf(rbx - ltx, 0.0f), hv = fmaxf(rby - lty, 0.0f);
        float inter = wv * hv;
        float iou = inter / (ia + ja - inter);
        if (iou > 0.6f) atomicAnd(&liveC[u >> 6], ~(1ull << (u & 63)));
      }
      __syncthreads();
    }
  }

  // resolve slot keys: walk entries via kr; fallback entries already written; rest = ALLF
  if (tid < 100) {
    if (tid < keptW)      slotkey_of(ws, b)[tid] = kr[keeplist[tid]];
    else if (tid >= kept) slotkey_of(ws, b)[tid] = ALLF;
  }
}

// ---------------- K5: parallel outputs (grid 16 x 10, 256 thr) ----------------
__global__ __launch_bounds__(256) void k_out(Ptrs P, float* out) {
  int b = blockIdx.x, part = blockIdx.y;   // 10 slots per block
  int s0 = part * 10;
  int tid = threadIdx.x;
  const u64* skl = slotkey_of(P.ws, b);

  if (tid < 10) {
    int s = s0 + tid;
    u64 key = skl[s];
    float os = -1.0f, oc = -1.0f;
    float4 bx = make_float4(-1.0f, -1.0f, -1.0f, -1.0f);
    if (key != ALLF) {
      int gid = (int)(key & 0x7FFF);
      os = __uint_as_float(~(u32)(key >> 15));
      oc = (float)((u16*)(P.ws + CLSI_OFF))[(size_t)b * TOTAL_G + gid];
      bx = decode_box(P, b, gid);
    }
    out[b * 100 + s] = os;
    out[1600 + b * 100 + s] = oc;
    *(float4*)(out + 3200 + (size_t)(b * 100 + s) * 4) = bx;
  }

  for (int t = tid; t < 800; t += 256) {
    int sl = t / 80, k = t - sl * 80;
    int s = s0 + sl;
    u64 key = skl[s];
    float val = -1.0f;
    if (key != ALLF) {
      int gid = (int)(key & 0x7FFF);
      int lev, idx, nl; levinfo(gid, lev, idx, nl);
      const float* cp;
      if      (lev == 0) cp = P.cls0;
      else if (lev == 1) cp = P.cls1;
      else if (lev == 2) cp = P.cls2;
      else if (lev == 3) cp = P.cls3;
      else               cp = P.cls4;
      val = sigd(cp[(size_t)(b * nl + idx) * 80 + k]);
    }
    out[9600 + (size_t)(b * 100 + s) * 80 + k] = val;
  }
}

extern "C" void kernel_launch(void* const* d_in, const int* in_sizes, int n_in,
                              void* d_out, int out_size, void* d_ws, size_t ws_size,
                              hipStream_t stream) {
  (void)in_sizes; (void)n_in; (void)out_size; (void)ws_size;
  Ptrs P;
  P.cls0 = (const float*)d_in[0];  P.reg0 = (const float*)d_in[1];
  P.ctr0 = (const float*)d_in[2];  P.pos0 = (const float*)d_in[3];
  P.cls1 = (const float*)d_in[4];  P.reg1 = (const float*)d_in[5];
  P.ctr1 = (const float*)d_in[6];  P.pos1 = (const float*)d_in[7];
  P.cls2 = (const float*)d_in[8];  P.reg2 = (const float*)d_in[9];
  P.ctr2 = (const float*)d_in[10]; P.pos2 = (const float*)d_in[11];
  P.cls3 = (const float*)d_in[12]; P.reg3 = (const float*)d_in[13];
  P.ctr3 = (const float*)d_in[14]; P.pos3 = (const float*)d_in[15];
  P.cls4 = (const float*)d_in[16]; P.reg4 = (const float*)d_in[17];
  P.ctr4 = (const float*)d_in[18]; P.pos4 = (const float*)d_in[19];
  P.ws = (char*)d_ws;

  k_score<<<dim3(267, 16), 256, 0, stream>>>(P);
  k_prep<<<16, 1024, 0, stream>>>(P);
  k_mask<<<dim3(4, 16), 1024, 0, stream>>>(P);
  k_reduce<<<16, 256, 0, stream>>>(P);
  k_out<<<dim3(16, 10), 256, 0, stream>>>(P, (float*)d_out);
}

// Round 15
// 94.382 us; speedup vs baseline: 1.6462x; 1.0178x over previous
//
#include <hip/hip_runtime.h>
#include <math.h>

#define TOTAL_G 17064
#define BATCHN  16
#define ALLF    0xFFFFFFFFFFFFFFFFull
// valid <=> score > 0.01f <=> scorebits > 0x3C23D70A <=> (key>>15) < 0xC3DC28F5
#define INVALID_HI 0xC3DC28F5u

typedef unsigned long long u64;
typedef unsigned int u32;
typedef unsigned short u16;

// ---- ws layout (bytes), total 3,336,576 ----
#define KEYS0_OFF   0          // u64[16][12800]  1,638,400
#define KEYS1_OFF   1638400    // u64[16][3200]     409,600
#define KEYS234_OFF 2048000    // u64[16][1088]     139,264
#define CLSI_OFF    2187264    // u16[16][17064]    546,048
#define NC_OFF      2733312    // int[32]: [16..31]=n512
#define T512_OFF    2733824    // u64[16]  (= Boundary-1; fallback predicate k > T512)
#define KR_OFF      2733952    // u64[16][512]       65,536
#define MSK_OFF     2799488    // u64[16][512*8]    524,288
#define SLOTK_OFF   3323776    // u64[16][100]       12,800

struct Ptrs {
  const float *cls0,*cls1,*cls2,*cls3,*cls4;
  const float *reg0,*reg1,*reg2,*reg3,*reg4;
  const float *ctr0,*ctr1,*ctr2,*ctr3,*ctr4;
  const float *pos0,*pos1,*pos2,*pos3,*pos4;
  char *ws;
};

__device__ __forceinline__ float sigd(float x) {
  return (float)(1.0 / (1.0 + exp(-(double)x)));
}
__device__ __forceinline__ float dexp(float x) {
  return (float)exp((double)x);
}
__device__ __forceinline__ void levinfo(int gid, int& lev, int& idx, int& nl) {
  if      (gid < 12800) { lev=0; idx=gid;        nl=12800; }
  else if (gid < 16000) { lev=1; idx=gid-12800;  nl=3200;  }
  else if (gid < 16800) { lev=2; idx=gid-16000;  nl=800;   }
  else if (gid < 17008) { lev=3; idx=gid-16800;  nl=208;   }
  else                  { lev=4; idx=gid-17008;  nl=56;    }
}

__device__ __forceinline__ u64* krank_of(char* ws, int b) {
  return (u64*)(ws + KR_OFF + (size_t)b * 4096);
}
__device__ __forceinline__ u64* msk_of(char* ws, int b) {
  return (u64*)(ws + MSK_OFF + (size_t)b * 32768);
}
__device__ __forceinline__ u64* slotkey_of(char* ws, int b) {
  return (u64*)(ws + SLOTK_OFF + (size_t)b * 800);
}

// exact box decode (identical everywhere -> deterministic)
__device__ __forceinline__ float4 decode_box(const Ptrs& P, int b, int gid) {
  int lev, idx, nl; levinfo(gid, lev, idx, nl);
  const float *rp, *pp;
  if      (lev == 0) { rp = P.reg0; pp = P.pos0; }
  else if (lev == 1) { rp = P.reg1; pp = P.pos1; }
  else if (lev == 2) { rp = P.reg2; pp = P.pos2; }
  else if (lev == 3) { rp = P.reg3; pp = P.pos3; }
  else               { rp = P.reg4; pp = P.pos4; }
  float4 rv = *(const float4*)(rp + (size_t)(b * nl + idx) * 4);
  float2 pv = *(const float2*)(pp + (size_t)(b * nl + idx) * 2);
  float e0 = dexp(rv.x), e1 = dexp(rv.y), e2 = dexp(rv.z), e3 = dexp(rv.w);
  float x1 = truncf(pv.x - e0), y1 = truncf(pv.y - e1);
  float x2 = truncf(pv.x + e2), y2 = truncf(pv.y + e3);
  x1 = fmaxf(x1, 0.0f); y1 = fmaxf(y1, 0.0f);
  x2 = fminf(x2, 1023.0f); y2 = fminf(y2, 799.0f);
  return make_float4(x1, y1, x2, y2);
}

// ---------------- K1: LDS-staged, 4-threads-per-position score / argmax / key ----------------
__global__ __launch_bounds__(256) void k_score(Ptrs P) {
  __shared__ float4 sk4[64 * 20];   // 64 positions x 320 B = 20 KB
  int b = blockIdx.y;
  int tid = threadIdx.x;
  int p0 = blockIdx.x * 64;

  #pragma unroll
  for (int it = 0; it < 5; ++it) {
    int t4 = it * 256 + tid;
    int g = p0 + t4 / 20;
    if (g < TOTAL_G) {
      int sub = t4 - (t4 / 20) * 20;
      int lev, idx, nl; levinfo(g, lev, idx, nl);
      const float* clsb;
      if      (lev == 0) clsb = P.cls0;
      else if (lev == 1) clsb = P.cls1;
      else if (lev == 2) clsb = P.cls2;
      else if (lev == 3) clsb = P.cls3;
      else               clsb = P.cls4;
      sk4[t4] = ((const float4*)(clsb + (size_t)(b * nl + idx) * 80))[sub];
    }
  }
  __syncthreads();

  int lp = tid >> 2, q = tid & 3;
  int g = p0 + lp;
  if (g >= TOTAL_G) return;

  const float4* my4 = &sk4[lp * 20 + q * 5];
  float m = -INFINITY, m2 = -INFINITY; int mi = 0;
  #pragma unroll
  for (int k = 0; k < 5; ++k) {
    float4 v = my4[k];
    int base = q * 20 + 4 * k;
    if (v.x > m) { m2 = m; m = v.x; mi = base+0; } else if (v.x > m2) m2 = v.x;
    if (v.y > m) { m2 = m; m = v.y; mi = base+1; } else if (v.y > m2) m2 = v.y;
    if (v.z > m) { m2 = m; m = v.z; mi = base+2; } else if (v.z > m2) m2 = v.z;
    if (v.w > m) { m2 = m; m = v.w; mi = base+3; } else if (v.w > m2) m2 = v.w;
  }
  #pragma unroll
  for (int xw = 1; xw <= 2; xw <<= 1) {
    float om  = __shfl_xor(m,  xw);
    float om2 = __shfl_xor(m2, xw);
    int   omi = __shfl_xor(mi, xw);
    bool take = (om > m) || (om == m && omi < mi);
    float lm  = take ? m : om;
    float wm2 = take ? om2 : m2;
    if (take) { m = om; mi = omi; }
    m2 = fmaxf(lm, wm2);
  }

  float thr = fminf(m - 1e-3f, 9.0f);
  float pmax; int ci;
  if (m2 >= thr) {
    // rare exact path: per-element sigmoid argmax among candidates >= thr
    float pv = -1.0f; int pi = 0x7fffffff;
    #pragma unroll 1
    for (int k = 0; k < 5; ++k) {
      float4 v = my4[k];
      float xs[4] = {v.x, v.y, v.z, v.w};
      #pragma unroll
      for (int e = 0; e < 4; ++e) {
        if (xs[e] >= thr) {
          float p = sigd(xs[e]);
          if (p > pv) { pv = p; pi = q * 20 + 4 * k + e; }
        }
      }
    }
    #pragma unroll
    for (int xw = 1; xw <= 2; xw <<= 1) {
      float ov = __shfl_xor(pv, xw);
      int   oi = __shfl_xor(pi, xw);
      if (ov > pv || (ov == pv && oi < pi)) { pv = ov; pi = oi; }
    }
    pmax = pv; ci = pi;
  } else {
    pmax = sigd(m); ci = mi;
  }

  if (q == 0) {
    int lev, idx, nl; levinfo(g, lev, idx, nl);
    const float* ctrb;
    if      (lev == 0) ctrb = P.ctr0;
    else if (lev == 1) ctrb = P.ctr1;
    else if (lev == 2) ctrb = P.ctr2;
    else if (lev == 3) ctrb = P.ctr3;
    else               ctrb = P.ctr4;
    float tc = ctrb[(size_t)b * nl + idx];
    float csig = sigd(tc);
    float prod = pmax * csig;
    float s = (float)sqrt((double)prod);
    ((u16*)(P.ws + CLSI_OFF))[(size_t)b * TOTAL_G + g] = (u16)ci;
    unsigned hi = ~__float_as_uint(s);
    u64 key = ((u64)hi << 15) | (unsigned)g;
    if      (lev == 0) ((u64*)(P.ws + KEYS0_OFF))  [(size_t)b * 12800 + idx] = key;
    else if (lev == 1) ((u64*)(P.ws + KEYS1_OFF))  [(size_t)b * 3200  + idx] = key;
    else               ((u64*)(P.ws + KEYS234_OFF))[(size_t)b * 1088  + (g - 16000)] = key;
  }
}

__device__ __forceinline__ u64 loadkey(const Ptrs& P, int b, int u) {
  if (u < 12800) return ((const u64*)(P.ws + KEYS0_OFF))  [(size_t)b * 12800 + u];
  if (u < 16000) return ((const u64*)(P.ws + KEYS1_OFF))  [(size_t)b * 3200  + (u - 12800)];
  return               ((const u64*)(P.ws + KEYS234_OFF))[(size_t)b * 1088  + (u - 16000)];
}
// paired load; u even; segment boundaries (12800/16000) even so no crossing.
// u up to 18430 reads garbage within ws (guarded out by u < TOTAL_G checks).
__device__ __forceinline__ ulonglong2 loadkey2(const Ptrs& P, int b, int u) {
  if (u < 12800) return *(const ulonglong2*)((const u64*)(P.ws + KEYS0_OFF)   + (size_t)b * 12800 + u);
  if (u < 16000) return *(const ulonglong2*)((const u64*)(P.ws + KEYS1_OFF)   + (size_t)b * 3200  + (u - 12800));
  return               *(const ulonglong2*)((const u64*)(P.ws + KEYS234_OFF) + (size_t)b * 1088  + (u - 16000));
}
__device__ __forceinline__ bool keep_pred(u64 k, int u, u64 T0, u64 T1) {
  bool valid = (u32)(k >> 15) < INVALID_HI;
  bool sel = (u < 12800) ? (k <= T0) : ((u < 16000) ? (k <= T1) : true);
  return valid && sel;
}

// ---------------- K2: in-block boundary + compact + rank + decode + mask (grid 4 x 16) ----------------
// Boundary: first 12-bit bin (key bits [40:29]) where cum >= 512 -> working set
// = valid keys < Boundary (TRUE PREFIX of global key order, n512 < 512); if cum
// never reaches 512, Boundary = first invalid key. Exact fallback in k_reduce
// covers keeps beyond the prefix. All 4 quadrant blocks derive bit-identical
// Boundary and skey[] (order-independent LDS-atomic sums + ordered ballot scatter).
__global__ __launch_bounds__(1024) void k_mask(Ptrs P) {
  __shared__ union USh {
    u32 H[4][4096];                                                      // 64 KB
    struct { float4 sbox[512]; u64 smaskR[4096]; u16 parts[1024]; } M;   // 42 KB
  } U;
  __shared__ u64 skey[512];
  __shared__ u16 srank[512];
  __shared__ int wbase[144];
  __shared__ int sN5;
  __shared__ u64 sBoundary;
  int qi = blockIdx.x, b = blockIdx.y;
  int tid = threadIdx.x, wid = tid >> 6, lane = tid & 63;
  int rep = wid & 3;
  char* ws = P.ws;

  // phase 1: histogram scan (2 keys/thread, 4 LDS replicas)
  for (int i = tid; i < 4 * 4096; i += 1024) (&U.H[0][0])[i] = 0;
  __syncthreads();
  for (int it = 0; it < 9; ++it) {
    int u = it * 2048 + tid * 2;
    if (u >= TOTAL_G) break;
    ulonglong2 kk = loadkey2(P, b, u);
    if ((u32)(kk.x >> 15) < INVALID_HI)
      atomicAdd(&U.H[rep][(u32)(kk.x >> 29) & 0xFFF], 1u);
    if (u + 1 < TOTAL_G && (u32)(kk.y >> 15) < INVALID_HI)
      atomicAdd(&U.H[rep][(u32)(kk.y >> 29) & 0xFFF], 1u);
  }
  __syncthreads();
  for (int i = tid; i < 4096; i += 1024)
    U.H[0][i] = U.H[0][i] + U.H[1][i] + U.H[2][i] + U.H[3][i];
  __syncthreads();

  // phase 2: single-wave two-level cumsum -> first bin where cum >= 512
  if (wid == 0) {
    u32 ssum = 0;
    #pragma unroll 8
    for (int i = 0; i < 64; ++i) {
      int ii = (i + lane) & 63;
      ssum += U.H[0][(lane << 6) + ii];
    }
    u32 inc = ssum;
    for (int o = 1; o < 64; o <<= 1) { u32 v = __shfl_up(inc, o); if (lane >= o) inc += v; }
    u64 ball = __ballot(inc >= 512u);
    if (!ball) {
      if (lane == 0) sBoundary = ((u64)INVALID_HI << 15);   // all valid keys
    } else {
      int Wq = __ffsll(ball) - 1;
      u32 cumBefore = __shfl(inc - ssum, Wq);
      u32 v2 = U.H[0][(Wq << 6) + lane];
      u32 inc2 = v2;
      for (int o = 1; o < 64; o <<= 1) { u32 x = __shfl_up(inc2, o); if (lane >= o) inc2 += x; }
      u64 ball2 = __ballot(cumBefore + inc2 >= 512u);
      int l2 = __ffsll(ball2) - 1;
      if (lane == 0) {
        int d = (Wq << 6) + l2;
        sBoundary = (48ull << 41) | ((u64)d << 29);
      }
    }
  }
  __syncthreads();
  u64 Boundary = sBoundary;
  if (qi == 0 && tid == 0) ((u64*)(ws + T512_OFF))[b] = Boundary - 1;

  // phase 3: per-wave keep counts, 2 keys/thread
  for (int it = 0; it < 9; ++it) {
    int u = it * 2048 + tid * 2;
    ulonglong2 kk = loadkey2(P, b, u);
    bool k0 = (u     < TOTAL_G) && ((u32)(kk.x >> 15) < INVALID_HI) && (kk.x < Boundary);
    bool k1 = (u + 1 < TOTAL_G) && ((u32)(kk.y >> 15) < INVALID_HI) && (kk.y < Boundary);
    u64 b0 = __ballot(k0), b1 = __ballot(k1);
    if (lane == 0) wbase[it * 16 + wid] = __popcll(b0) + __popcll(b1);
  }
  __syncthreads();
  if (wid == 0) {
    int carry = 0;
    for (int base = 0; base < 144; base += 64) {
      int idx = base + lane;
      int v = (idx < 144) ? wbase[idx] : 0;
      int inc = v;
      for (int o = 1; o < 64; o <<= 1) { int x = __shfl_up(inc, o); if (lane >= o) inc += x; }
      if (idx < 144) wbase[idx] = inc - v + carry;
      carry += __shfl(inc, 63);
    }
    if (lane == 0) sN5 = carry;
  }
  __syncthreads();
  int n512 = sN5;                       // < 512 by construction
  if (qi == 0 && tid == 0) ((int*)(ws + NC_OFF))[16 + b] = n512;

  // phase 4: ordered scatter of the prefix set into LDS
  for (int it = 0; it < 9; ++it) {
    int u = it * 2048 + tid * 2;
    ulonglong2 kk = loadkey2(P, b, u);
    bool k0 = (u     < TOTAL_G) && ((u32)(kk.x >> 15) < INVALID_HI) && (kk.x < Boundary);
    bool k1 = (u + 1 < TOTAL_G) && ((u32)(kk.y >> 15) < INVALID_HI) && (kk.y < Boundary);
    u64 b0 = __ballot(k0), b1 = __ballot(k1);
    u64 lm = (1ull << lane) - 1ull;
    int pos0 = wbase[it * 16 + wid] + __popcll(b0 & lm) + __popcll(b1 & lm);
    int pos1 = pos0 + (k0 ? 1 : 0);
    if (k0) skey[pos0] = kk.x;
    if (k1) skey[pos1] = kk.y;
  }
  __syncthreads();

  // phase 5: decode + pad (first union-M writes — histogram dead for several barriers)
  if (tid < 512) {
    if (tid < n512) {
      U.M.sbox[tid] = decode_box(P, b, (int)(skey[tid] & 0x7FFF));
    } else {
      skey[tid] = (ALLF - 511) + (u64)tid;   // distinct, > any real key
      U.M.sbox[tid] = make_float4(-1e30f, -1e30f, -1e30f, -1e30f);
    }
  }
  for (int i = tid; i < 512 * 8; i += 1024) U.M.smaskR[i] = 0ull;
  __syncthreads();

  // phase 6: rank all 512 by key
  {
    int t2 = tid & 511, half = tid >> 9;
    u64 mykey = skey[t2];
    int jb = half << 8, cnt = 0;
    #pragma unroll 4
    for (int j = jb; j < jb + 256; ++j) cnt += (skey[j] < mykey) ? 1 : 0;
    U.M.parts[tid] = (u16)cnt;
  }
  __syncthreads();
  if (tid < 512) srank[tid] = (u16)(U.M.parts[tid] + U.M.parts[tid + 512]);
  __syncthreads();

  // phase 7: suppression bits in rank space (rotated j-scan, conflict-free)
  int i = qi * 128 + (tid >> 3);
  int w = tid & 7;
  float4 bi = U.M.sbox[i];
  u64 ki = skey[i];
  int ri = srank[i];
  float ia = (bi.z - bi.x) * (bi.w - bi.y);
  #pragma unroll 8
  for (int bj = 0; bj < 64; ++bj) {
    int jj = (bj + w) & 63;
    int j = (w << 6) | jj;
    u64 kj = skey[j];
    if (ki < kj) {
      float4 bj4 = U.M.sbox[j];
      float ja  = (bj4.z - bj4.x) * (bj4.w - bj4.y);
      float ltx = fmaxf(bi.x, bj4.x), lty = fmaxf(bi.y, bj4.y);
      float rbx = fminf(bi.z, bj4.z), rby = fminf(bi.w, bj4.w);
      float wv = fmaxf(rbx - ltx, 0.0f), hv = fmaxf(rby - lty, 0.0f);
      float inter = wv * hv;
      float iou = inter / (ia + ja - inter);   // exact: integer-valued fp32
      if (iou > 0.6f) {
        int rj = srank[j];
        atomicOr(&U.M.smaskR[ri * 8 + (rj >> 6)], 1ull << (rj & 63));
      }
    }
  }
  __syncthreads();

  {
    int il = tid >> 3, ww = tid & 7;
    int ig = qi * 128 + il;
    if (ig < n512) {
      int r = srank[ig];
      msk_of(ws, b)[r * 8 + ww] = U.M.smaskR[r * 8 + ww];
      if (ww == 0) krank_of(ws, b)[r] = skey[ig];
    }
  }
}

// ---------------- 256-thread exact radix select (fallback only; no early exits) ----------------
__device__ u64 select256(const u64* keys, int n, int t0, u32* hist, u64* shP, int* shT) {
  u64 Pfx = 3; int t = t0;
  const int SS[4] = {33, 21, 9, 0};
  const int WW[4] = {12, 12, 12, 9};
  for (int p = 0; p < 4; ++p) {
    int s = SS[p], wb = WW[p];
    u32 dmask = (1u << wb) - 1u;
    for (int i = threadIdx.x; i < 4096; i += 256) hist[i] = 0;
    __syncthreads();
    for (int i = threadIdx.x; i < n; i += 256) {
      u64 k = keys[i];
      if ((k >> (s + wb)) == Pfx) atomicAdd(&hist[(u32)(k >> s) & dmask], 1u);
    }
    __syncthreads();
    if (threadIdx.x < 64) {
      int lane = threadIdx.x;
      u32 ssum = 0;
      for (int i = 0; i < 64; ++i) ssum += hist[(lane << 6) + ((i + lane) & 63)];
      u32 inc = ssum;
      for (int o = 1; o < 64; o <<= 1) { u32 v = __shfl_up(inc, o); if (lane >= o) inc += v; }
      u64 ball = __ballot(inc >= (u32)t);
      int Wq = __ffsll(ball) - 1;
      u32 cumBefore = __shfl(inc - ssum, Wq);
      u32 v2 = hist[(Wq << 6) + lane];
      u32 inc2 = v2;
      for (int o = 1; o < 64; o <<= 1) { u32 x = __shfl_up(inc2, o); if (lane >= o) inc2 += x; }
      u64 ball2 = __ballot(cumBefore + inc2 >= (u32)t);
      int l2 = __ffsll(ball2) - 1;
      u32 cumB2 = __shfl(cumBefore + inc2 - v2, l2);
      if (lane == 0) { *shP = (Pfx << wb) | (u32)((Wq << 6) + l2); *shT = t - (int)cumB2; }
    }
    __syncthreads();
    Pfx = *shP; t = *shT;
    __syncthreads();
  }
  return Pfx;   // final pass (s=0) yields the full 47-bit key
}

// ---------------- K3: greedy ffs walk + fallback + slotkey (grid 16, 256 thr) ----------------
__global__ __launch_bounds__(256) void k_reduce(Ptrs P) {
  __shared__ u64 smask[4096];       // 32 KB
  __shared__ u32 keeplist[100];     // ranks (walk phase only)
  __shared__ int keptS;
  __shared__ u64 liveC[267];        // fallback: live bits over gid space
  __shared__ union UF {
    u32 hist[4096];                 // 16 KB (fallback selects)
    struct { u64 pk[256]; int pc[256]; float4 fkb[100]; } F;
  } UF_;
  __shared__ u64 shP; __shared__ int shT;
  __shared__ u64 bk; __shared__ int bc2;

  int b = blockIdx.x;
  int tid = threadIdx.x;
  char* ws = P.ws;
  int n512 = ((int*)(ws + NC_OFF))[16 + b];
  const u64* kr = krank_of(ws, b);

  const u64* gmask = msk_of(ws, b);
  for (int t = tid; t < 4096; t += 256) smask[t] = gmask[t];
  __syncthreads();

  // single-wave barrier-free greedy walk over ranks [0, n512)
  if (tid < 64) {
    int lane = tid;
    u64 lw = 0;
    if (lane < 8) {
      int lo = lane << 6;
      int c = n512 - lo; if (c < 0) c = 0; if (c > 64) c = 64;
      lw = (c >= 64) ? ALLF : ((c > 0) ? ((1ull << c) - 1ull) : 0ull);
    }
    int kept = 0;
    while (kept < 100) {
      bool nz = (lane < 8) && (lw != 0ull);
      u64 bal = __ballot(nz);
      if (!bal) break;
      int W = __ffsll(bal) - 1;
      u64 wv = __shfl(lw, W);
      int bit = __ffsll(wv) - 1;
      int i = (W << 6) + bit;
      if (lane == 0) keeplist[kept] = (u32)i;
      kept++;
      if (lane == W) lw &= ~(1ull << bit);
      if (kept == 100) break;
      if (lane < 8) lw &= ~smask[i * 8 + lane];
    }
    if (lane == 0) keptS = kept;
  }
  __syncthreads();
  int kept = keptS;
  int keptW = kept;

  // fallback: keeps beyond the prefix (rare; exact)
  if (kept < 100) {
    u64 T0 = select256((const u64*)(ws + KEYS0_OFF) + (size_t)b * 12800, 12800, 1000,
                       UF_.hist, &shP, &shT);
    u64 T1 = select256((const u64*)(ws + KEYS1_OFF) + (size_t)b * 3200, 3200, 1000,
                       UF_.hist, &shP, &shT);
    u64 T512 = ((u64*)(ws + T512_OFF))[b];
    for (int w = tid; w < 267; w += 256) {
      int lo = w << 6;
      u64 m = 0;
      for (int e = 0; e < 64; ++e) {
        int u = lo + e;
        if (u < TOTAL_G) {
          u64 k = loadkey(P, b, u);
          if (keep_pred(k, u, T0, T1) && k > T512) m |= (1ull << e);
        }
      }
      liveC[w] = m;
    }
    if (tid < kept) UF_.F.fkb[tid] = decode_box(P, b, (int)(kr[keeplist[tid]] & 0x7FFF));
    __syncthreads();

    // seed suppression from already-kept items
    for (int k2 = 0; k2 < kept; ++k2) {
      float4 bi = UF_.F.fkb[k2];
      float ia = (bi.z - bi.x) * (bi.w - bi.y);
      for (int u = tid; u < TOTAL_G; u += 256) {
        if (!((liveC[u >> 6] >> (u & 63)) & 1ull)) continue;
        float4 bj4 = decode_box(P, b, u);
        float ja  = (bj4.z - bj4.x) * (bj4.w - bj4.y);
        float ltx = fmaxf(bi.x, bj4.x), lty = fmaxf(bi.y, bj4.y);
        float rbx = fminf(bi.z, bj4.z), rby = fminf(bi.w, bj4.w);
        float wv = fmaxf(rbx - ltx, 0.0f), hv = fmaxf(rby - lty, 0.0f);
        float inter = wv * hv;
        float iou = inter / (ia + ja - inter);
        if (iou > 0.6f) atomicAnd(&liveC[u >> 6], ~(1ull << (u & 63)));
      }
    }
    __syncthreads();

    // selection-by-min-key loop
    while (kept < 100) {
      u64 mymin = ALLF; int myc = -1;
      for (int u = tid; u < TOTAL_G; u += 256) {
        if (!((liveC[u >> 6] >> (u & 63)) & 1ull)) continue;
        u64 k = loadkey(P, b, u);
        if (k < mymin) { mymin = k; myc = u; }
      }
      UF_.F.pk[tid] = mymin; UF_.F.pc[tid] = myc;
      __syncthreads();
      if (tid < 64) {
        u64 m = UF_.F.pk[tid]; int c0 = UF_.F.pc[tid];
        #pragma unroll
        for (int o = 64; o < 256; o += 64)
          if (UF_.F.pk[tid + o] < m) { m = UF_.F.pk[tid + o]; c0 = UF_.F.pc[tid + o]; }
        for (int o = 32; o > 0; o >>= 1) {
          u64 om = __shfl_down(m, o); int oc = __shfl_down(c0, o);
          if (om < m) { m = om; c0 = oc; }
        }
        if (tid == 0) { bk = m; bc2 = c0; }
      }
      __syncthreads();
      if (bk == ALLF) break;
      int cs = bc2;
      if (tid == 0) {
        slotkey_of(ws, b)[kept] = bk;     // fallback keeps write slotkey directly
        atomicAnd(&liveC[cs >> 6], ~(1ull << (cs & 63)));
      }
      __syncthreads();
      kept++;
      if (kept == 100) break;
      float4 bi = decode_box(P, b, cs);
      float ia = (bi.z - bi.x) * (bi.w - bi.y);
      for (int u = tid; u < TOTAL_G; u += 256) {
        if (!((liveC[u >> 6] >> (u & 63)) & 1ull)) continue;
        float4 bj4 = decode_box(P, b, u);
        float ja  = (bj4.z - bj4.x) * (bj4.w - bj4.y);
        float ltx = fmaxf(bi.x, bj4.x), lty = fmaxf(bi.y, bj4.y);
        float rbx = fminf(bi.z, bj4.z), rby = fminf(bi.w, bj4.w);
        float wv = fmaxf(rbx - ltx, 0.0f), hv = fmaxf(rby - lty, 0.0f);
        float inter = wv * hv;
        float iou = inter / (ia + ja - inter);
        if (iou > 0.6f) atomicAnd(&liveC[u >> 6], ~(1ull << (u & 63)));
      }
      __syncthreads();
    }
  }

  // resolve slot keys: walk entries via kr; fallback entries already written; rest = ALLF
  if (tid < 100) {
    if (tid < keptW)      slotkey_of(ws, b)[tid] = kr[keeplist[tid]];
    else if (tid >= kept) slotkey_of(ws, b)[tid] = ALLF;
  }
}

// ---------------- K4: parallel outputs (grid 16 x 10, 256 thr) ----------------
__global__ __launch_bounds__(256) void k_out(Ptrs P, float* out) {
  int b = blockIdx.x, part = blockIdx.y;   // 10 slots per block
  int s0 = part * 10;
  int tid = threadIdx.x;
  const u64* skl = slotkey_of(P.ws, b);

  if (tid < 10) {
    int s = s0 + tid;
    u64 key = skl[s];
    float os = -1.0f, oc = -1.0f;
    float4 bx = make_float4(-1.0f, -1.0f, -1.0f, -1.0f);
    if (key != ALLF) {
      int gid = (int)(key & 0x7FFF);
      os = __uint_as_float(~(u32)(key >> 15));
      oc = (float)((u16*)(P.ws + CLSI_OFF))[(size_t)b * TOTAL_G + gid];
      bx = decode_box(P, b, gid);
    }
    out[b * 100 + s] = os;
    out[1600 + b * 100 + s] = oc;
    *(float4*)(out + 3200 + (size_t)(b * 100 + s) * 4) = bx;
  }

  for (int t = tid; t < 800; t += 256) {
    int sl = t / 80, k = t - sl * 80;
    int s = s0 + sl;
    u64 key = skl[s];
    float val = -1.0f;
    if (key != ALLF) {
      int gid = (int)(key & 0x7FFF);
      int lev, idx, nl; levinfo(gid, lev, idx, nl);
      const float* cp;
      if      (lev == 0) cp = P.cls0;
      else if (lev == 1) cp = P.cls1;
      else if (lev == 2) cp = P.cls2;
      else if (lev == 3) cp = P.cls3;
      else               cp = P.cls4;
      val = sigd(cp[(size_t)(b * nl + idx) * 80 + k]);
    }
    out[9600 + (size_t)(b * 100 + s) * 80 + k] = val;
  }
}

extern "C" void kernel_launch(void* const* d_in, const int* in_sizes, int n_in,
                              void* d_out, int out_size, void* d_ws, size_t ws_size,
                              hipStream_t stream) {
  (void)in_sizes; (void)n_in; (void)out_size; (void)ws_size;
  Ptrs P;
  P.cls0 = (const float*)d_in[0];  P.reg0 = (const float*)d_in[1];
  P.ctr0 = (const float*)d_in[2];  P.pos0 = (const float*)d_in[3];
  P.cls1 = (const float*)d_in[4];  P.reg1 = (const float*)d_in[5];
  P.ctr1 = (const float*)d_in[6];  P.pos1 = (const float*)d_in[7];
  P.cls2 = (const float*)d_in[8];  P.reg2 = (const float*)d_in[9];
  P.ctr2 = (const float*)d_in[10]; P.pos2 = (const float*)d_in[11];
  P.cls3 = (const float*)d_in[12]; P.reg3 = (const float*)d_in[13];
  P.ctr3 = (const float*)d_in[14]; P.pos3 = (const float*)d_in[15];
  P.cls4 = (const float*)d_in[16]; P.reg4 = (const float*)d_in[17];
  P.ctr4 = (const float*)d_in[18]; P.pos4 = (const float*)d_in[19];
  P.ws = (char*)d_ws;

  k_score<<<dim3(267, 16), 256, 0, stream>>>(P);
  k_mask<<<dim3(4, 16), 1024, 0, stream>>>(P);
  k_reduce<<<16, 256, 0, stream>>>(P);
  k_out<<<dim3(16, 10), 256, 0, stream>>>(P, (float*)d_out);
}

// Round 16
// 91.359 us; speedup vs baseline: 1.7006x; 1.0331x over previous
//
#include <hip/hip_runtime.h>
#include <math.h>

#define TOTAL_G 17064
#define BATCHN  16
#define ALLF    0xFFFFFFFFFFFFFFFFull
// valid <=> score > 0.01f <=> scorebits > 0x3C23D70A <=> (key>>15) < 0xC3DC28F5
#define INVALID_HI 0xC3DC28F5u

typedef unsigned long long u64;
typedef unsigned int u32;
typedef unsigned short u16;

// ---- ws layout (bytes), total 3,336,576 ----
#define KEYS0_OFF   0          // u64[16][12800]  1,638,400
#define KEYS1_OFF   1638400    // u64[16][3200]     409,600
#define KEYS234_OFF 2048000    // u64[16][1088]     139,264
#define CLSI_OFF    2187264    // u16[16][17064]    546,048
#define NC_OFF      2733312    // int[32]: [16..31]=n512
#define T512_OFF    2733824    // u64[16]  (= Boundary-1; fallback predicate k > T512)
#define KR_OFF      2733952    // u64[16][512]       65,536
#define MSK_OFF     2799488    // u64[16][512*8]    524,288
#define SLOTK_OFF   3323776    // u64[16][100]       12,800

struct Ptrs {
  const float *cls0,*cls1,*cls2,*cls3,*cls4;
  const float *reg0,*reg1,*reg2,*reg3,*reg4;
  const float *ctr0,*ctr1,*ctr2,*ctr3,*ctr4;
  const float *pos0,*pos1,*pos2,*pos3,*pos4;
  char *ws;
};

__device__ __forceinline__ float sigd(float x) {
  return (float)(1.0 / (1.0 + exp(-(double)x)));
}
__device__ __forceinline__ float dexp(float x) {
  return (float)exp((double)x);
}
__device__ __forceinline__ void levinfo(int gid, int& lev, int& idx, int& nl) {
  if      (gid < 12800) { lev=0; idx=gid;        nl=12800; }
  else if (gid < 16000) { lev=1; idx=gid-12800;  nl=3200;  }
  else if (gid < 16800) { lev=2; idx=gid-16000;  nl=800;   }
  else if (gid < 17008) { lev=3; idx=gid-16800;  nl=208;   }
  else                  { lev=4; idx=gid-17008;  nl=56;    }
}

__device__ __forceinline__ u64* krank_of(char* ws, int b) {
  return (u64*)(ws + KR_OFF + (size_t)b * 4096);
}
__device__ __forceinline__ u64* msk_of(char* ws, int b) {
  return (u64*)(ws + MSK_OFF + (size_t)b * 32768);
}
__device__ __forceinline__ u64* slotkey_of(char* ws, int b) {
  return (u64*)(ws + SLOTK_OFF + (size_t)b * 800);
}

// exact box decode (identical everywhere -> deterministic)
__device__ __forceinline__ float4 decode_box(const Ptrs& P, int b, int gid) {
  int lev, idx, nl; levinfo(gid, lev, idx, nl);
  const float *rp, *pp;
  if      (lev == 0) { rp = P.reg0; pp = P.pos0; }
  else if (lev == 1) { rp = P.reg1; pp = P.pos1; }
  else if (lev == 2) { rp = P.reg2; pp = P.pos2; }
  else if (lev == 3) { rp = P.reg3; pp = P.pos3; }
  else               { rp = P.reg4; pp = P.pos4; }
  float4 rv = *(const float4*)(rp + (size_t)(b * nl + idx) * 4);
  float2 pv = *(const float2*)(pp + (size_t)(b * nl + idx) * 2);
  float e0 = dexp(rv.x), e1 = dexp(rv.y), e2 = dexp(rv.z), e3 = dexp(rv.w);
  float x1 = truncf(pv.x - e0), y1 = truncf(pv.y - e1);
  float x2 = truncf(pv.x + e2), y2 = truncf(pv.y + e3);
  x1 = fmaxf(x1, 0.0f); y1 = fmaxf(y1, 0.0f);
  x2 = fminf(x2, 1023.0f); y2 = fminf(y2, 799.0f);
  return make_float4(x1, y1, x2, y2);
}

// ---------------- K1: LDS-staged, 4-threads-per-position score / argmax / key ----------------
__global__ __launch_bounds__(256) void k_score(Ptrs P) {
  __shared__ float4 sk4[64 * 20];   // 64 positions x 320 B = 20 KB
  int b = blockIdx.y;
  int tid = threadIdx.x;
  int p0 = blockIdx.x * 64;

  #pragma unroll
  for (int it = 0; it < 5; ++it) {
    int t4 = it * 256 + tid;
    int g = p0 + t4 / 20;
    if (g < TOTAL_G) {
      int sub = t4 - (t4 / 20) * 20;
      int lev, idx, nl; levinfo(g, lev, idx, nl);
      const float* clsb;
      if      (lev == 0) clsb = P.cls0;
      else if (lev == 1) clsb = P.cls1;
      else if (lev == 2) clsb = P.cls2;
      else if (lev == 3) clsb = P.cls3;
      else               clsb = P.cls4;
      sk4[t4] = ((const float4*)(clsb + (size_t)(b * nl + idx) * 80))[sub];
    }
  }
  __syncthreads();

  int lp = tid >> 2, q = tid & 3;
  int g = p0 + lp;
  if (g >= TOTAL_G) return;

  const float4* my4 = &sk4[lp * 20 + q * 5];
  float m = -INFINITY, m2 = -INFINITY; int mi = 0;
  #pragma unroll
  for (int k = 0; k < 5; ++k) {
    float4 v = my4[k];
    int base = q * 20 + 4 * k;
    if (v.x > m) { m2 = m; m = v.x; mi = base+0; } else if (v.x > m2) m2 = v.x;
    if (v.y > m) { m2 = m; m = v.y; mi = base+1; } else if (v.y > m2) m2 = v.y;
    if (v.z > m) { m2 = m; m = v.z; mi = base+2; } else if (v.z > m2) m2 = v.z;
    if (v.w > m) { m2 = m; m = v.w; mi = base+3; } else if (v.w > m2) m2 = v.w;
  }
  #pragma unroll
  for (int xw = 1; xw <= 2; xw <<= 1) {
    float om  = __shfl_xor(m,  xw);
    float om2 = __shfl_xor(m2, xw);
    int   omi = __shfl_xor(mi, xw);
    bool take = (om > m) || (om == m && omi < mi);
    float lm  = take ? m : om;
    float wm2 = take ? om2 : m2;
    if (take) { m = om; mi = omi; }
    m2 = fmaxf(lm, wm2);
  }

  float thr = fminf(m - 1e-3f, 9.0f);
  float pmax; int ci;
  if (m2 >= thr) {
    // rare exact path: per-element sigmoid argmax among candidates >= thr
    float pv = -1.0f; int pi = 0x7fffffff;
    #pragma unroll 1
    for (int k = 0; k < 5; ++k) {
      float4 v = my4[k];
      float xs[4] = {v.x, v.y, v.z, v.w};
      #pragma unroll
      for (int e = 0; e < 4; ++e) {
        if (xs[e] >= thr) {
          float p = sigd(xs[e]);
          if (p > pv) { pv = p; pi = q * 20 + 4 * k + e; }
        }
      }
    }
    #pragma unroll
    for (int xw = 1; xw <= 2; xw <<= 1) {
      float ov = __shfl_xor(pv, xw);
      int   oi = __shfl_xor(pi, xw);
      if (ov > pv || (ov == pv && oi < pi)) { pv = ov; pi = oi; }
    }
    pmax = pv; ci = pi;
  } else {
    pmax = sigd(m); ci = mi;
  }

  if (q == 0) {
    int lev, idx, nl; levinfo(g, lev, idx, nl);
    const float* ctrb;
    if      (lev == 0) ctrb = P.ctr0;
    else if (lev == 1) ctrb = P.ctr1;
    else if (lev == 2) ctrb = P.ctr2;
    else if (lev == 3) ctrb = P.ctr3;
    else               ctrb = P.ctr4;
    float tc = ctrb[(size_t)b * nl + idx];
    float csig = sigd(tc);
    float prod = pmax * csig;
    float s = (float)sqrt((double)prod);
    ((u16*)(P.ws + CLSI_OFF))[(size_t)b * TOTAL_G + g] = (u16)ci;
    unsigned hi = ~__float_as_uint(s);
    u64 key = ((u64)hi << 15) | (unsigned)g;
    if      (lev == 0) ((u64*)(P.ws + KEYS0_OFF))  [(size_t)b * 12800 + idx] = key;
    else if (lev == 1) ((u64*)(P.ws + KEYS1_OFF))  [(size_t)b * 3200  + idx] = key;
    else               ((u64*)(P.ws + KEYS234_OFF))[(size_t)b * 1088  + (g - 16000)] = key;
  }
}

__device__ __forceinline__ u64 loadkey(const Ptrs& P, int b, int u) {
  if (u < 12800) return ((const u64*)(P.ws + KEYS0_OFF))  [(size_t)b * 12800 + u];
  if (u < 16000) return ((const u64*)(P.ws + KEYS1_OFF))  [(size_t)b * 3200  + (u - 12800)];
  return               ((const u64*)(P.ws + KEYS234_OFF))[(size_t)b * 1088  + (u - 16000)];
}
// paired load; u even; segment boundaries (12800/16000) even so no crossing.
// u up to 18430 reads garbage within ws (guarded out by u < TOTAL_G checks).
__device__ __forceinline__ ulonglong2 loadkey2(const Ptrs& P, int b, int u) {
  if (u < 12800) return *(const ulonglong2*)((const u64*)(P.ws + KEYS0_OFF)   + (size_t)b * 12800 + u);
  if (u < 16000) return *(const ulonglong2*)((const u64*)(P.ws + KEYS1_OFF)   + (size_t)b * 3200  + (u - 12800));
  return               *(const ulonglong2*)((const u64*)(P.ws + KEYS234_OFF) + (size_t)b * 1088  + (u - 16000));
}
__device__ __forceinline__ bool keep_pred(u64 k, int u, u64 T0, u64 T1) {
  bool valid = (u32)(k >> 15) < INVALID_HI;
  bool sel = (u < 12800) ? (k <= T0) : ((u < 16000) ? (k <= T1) : true);
  return valid && sel;
}

// ---------------- K2: one-load boundary + compact + rank + decode + mask (grid 4 x 16) ----------------
// Keys are loaded ONCE into registers (9 x ulonglong2 per thread, fully unrolled
// so all loads are in flight together); histogram/count/scatter then run from
// registers — no repeated key scans. Boundary: first 12-bit bin (key bits
// [40:29]) where cum >= 512 -> working set = valid keys < Boundary (TRUE PREFIX,
// n512 < 512); if cum never reaches 512, Boundary = first invalid key. Exact
// fallback in k_reduce covers keeps beyond the prefix. All 4 quadrant blocks
// derive bit-identical Boundary and skey[].
__global__ __launch_bounds__(1024) void k_mask(Ptrs P) {
  __shared__ union USh {
    u32 H[4][4096];                                                      // 64 KB
    struct { float4 sbox[512]; u64 smaskR[4096]; u16 parts[1024]; } M;   // 42 KB
  } U;
  __shared__ u64 skey[512];
  __shared__ u16 srank[512];
  __shared__ int wbase[144];
  __shared__ int sN5;
  __shared__ u64 sBoundary;
  int qi = blockIdx.x, b = blockIdx.y;
  int tid = threadIdx.x, wid = tid >> 6, lane = tid & 63;
  int rep = wid & 3;
  char* ws = P.ws;

  // phase 0: preload all keys into registers (all 9 loads issue together)
  ulonglong2 kk[9];
  #pragma unroll
  for (int it = 0; it < 9; ++it) kk[it] = loadkey2(P, b, it * 2048 + tid * 2);

  // phase 1: histogram from registers (4 LDS replicas)
  for (int i = tid; i < 4 * 4096; i += 1024) (&U.H[0][0])[i] = 0;
  __syncthreads();
  #pragma unroll
  for (int it = 0; it < 9; ++it) {
    int u = it * 2048 + tid * 2;
    if (u < TOTAL_G && (u32)(kk[it].x >> 15) < INVALID_HI)
      atomicAdd(&U.H[rep][(u32)(kk[it].x >> 29) & 0xFFF], 1u);
    if (u + 1 < TOTAL_G && (u32)(kk[it].y >> 15) < INVALID_HI)
      atomicAdd(&U.H[rep][(u32)(kk[it].y >> 29) & 0xFFF], 1u);
  }
  __syncthreads();
  for (int i = tid; i < 4096; i += 1024)
    U.H[0][i] = U.H[0][i] + U.H[1][i] + U.H[2][i] + U.H[3][i];
  __syncthreads();

  // phase 2: single-wave two-level cumsum -> first bin where cum >= 512
  if (wid == 0) {
    u32 ssum = 0;
    #pragma unroll 8
    for (int i = 0; i < 64; ++i) {
      int ii = (i + lane) & 63;
      ssum += U.H[0][(lane << 6) + ii];
    }
    u32 inc = ssum;
    for (int o = 1; o < 64; o <<= 1) { u32 v = __shfl_up(inc, o); if (lane >= o) inc += v; }
    u64 ball = __ballot(inc >= 512u);
    if (!ball) {
      if (lane == 0) sBoundary = ((u64)INVALID_HI << 15);   // all valid keys
    } else {
      int Wq = __ffsll(ball) - 1;
      u32 cumBefore = __shfl(inc - ssum, Wq);
      u32 v2 = U.H[0][(Wq << 6) + lane];
      u32 inc2 = v2;
      for (int o = 1; o < 64; o <<= 1) { u32 x = __shfl_up(inc2, o); if (lane >= o) inc2 += x; }
      u64 ball2 = __ballot(cumBefore + inc2 >= 512u);
      int l2 = __ffsll(ball2) - 1;
      if (lane == 0) {
        int d = (Wq << 6) + l2;
        sBoundary = (48ull << 41) | ((u64)d << 29);
      }
    }
  }
  __syncthreads();
  u64 Boundary = sBoundary;
  if (qi == 0 && tid == 0) ((u64*)(ws + T512_OFF))[b] = Boundary - 1;

  // phase 3: per-wave keep counts from registers
  #pragma unroll
  for (int it = 0; it < 9; ++it) {
    int u = it * 2048 + tid * 2;
    bool k0 = (u     < TOTAL_G) && ((u32)(kk[it].x >> 15) < INVALID_HI) && (kk[it].x < Boundary);
    bool k1 = (u + 1 < TOTAL_G) && ((u32)(kk[it].y >> 15) < INVALID_HI) && (kk[it].y < Boundary);
    u64 b0 = __ballot(k0), b1 = __ballot(k1);
    if (lane == 0) wbase[it * 16 + wid] = __popcll(b0) + __popcll(b1);
  }
  __syncthreads();
  if (wid == 0) {
    int carry = 0;
    for (int base = 0; base < 144; base += 64) {
      int idx = base + lane;
      int v = (idx < 144) ? wbase[idx] : 0;
      int inc = v;
      for (int o = 1; o < 64; o <<= 1) { int x = __shfl_up(inc, o); if (lane >= o) inc += x; }
      if (idx < 144) wbase[idx] = inc - v + carry;
      carry += __shfl(inc, 63);
    }
    if (lane == 0) sN5 = carry;
  }
  __syncthreads();
  int n512 = sN5;                       // < 512 by construction
  if (qi == 0 && tid == 0) ((int*)(ws + NC_OFF))[16 + b] = n512;

  // phase 4: ordered scatter of the prefix set into LDS (from registers)
  #pragma unroll
  for (int it = 0; it < 9; ++it) {
    int u = it * 2048 + tid * 2;
    bool k0 = (u     < TOTAL_G) && ((u32)(kk[it].x >> 15) < INVALID_HI) && (kk[it].x < Boundary);
    bool k1 = (u + 1 < TOTAL_G) && ((u32)(kk[it].y >> 15) < INVALID_HI) && (kk[it].y < Boundary);
    u64 b0 = __ballot(k0), b1 = __ballot(k1);
    u64 lm = (1ull << lane) - 1ull;
    int pos0 = wbase[it * 16 + wid] + __popcll(b0 & lm) + __popcll(b1 & lm);
    int pos1 = pos0 + (k0 ? 1 : 0);
    if (k0) skey[pos0] = kk[it].x;
    if (k1) skey[pos1] = kk[it].y;
  }
  __syncthreads();

  // phase 5: decode + pad (first union-M writes — histogram dead for several barriers)
  if (tid < 512) {
    if (tid < n512) {
      U.M.sbox[tid] = decode_box(P, b, (int)(skey[tid] & 0x7FFF));
    } else {
      skey[tid] = (ALLF - 511) + (u64)tid;   // distinct, > any real key
      U.M.sbox[tid] = make_float4(-1e30f, -1e30f, -1e30f, -1e30f);
    }
  }
  for (int i = tid; i < 512 * 8; i += 1024) U.M.smaskR[i] = 0ull;
  __syncthreads();

  // phase 6: rank all 512 by key
  {
    int t2 = tid & 511, half = tid >> 9;
    u64 mykey = skey[t2];
    int jb = half << 8, cnt = 0;
    #pragma unroll 4
    for (int j = jb; j < jb + 256; ++j) cnt += (skey[j] < mykey) ? 1 : 0;
    U.M.parts[tid] = (u16)cnt;
  }
  __syncthreads();
  if (tid < 512) srank[tid] = (u16)(U.M.parts[tid] + U.M.parts[tid + 512]);
  __syncthreads();

  // phase 7: suppression bits in rank space (rotated j-scan, conflict-free)
  int i = qi * 128 + (tid >> 3);
  int w = tid & 7;
  float4 bi = U.M.sbox[i];
  u64 ki = skey[i];
  int ri = srank[i];
  float ia = (bi.z - bi.x) * (bi.w - bi.y);
  #pragma unroll 8
  for (int bj = 0; bj < 64; ++bj) {
    int jj = (bj + w) & 63;
    int j = (w << 6) | jj;
    u64 kj = skey[j];
    if (ki < kj) {
      float4 bj4 = U.M.sbox[j];
      float ja  = (bj4.z - bj4.x) * (bj4.w - bj4.y);
      float ltx = fmaxf(bi.x, bj4.x), lty = fmaxf(bi.y, bj4.y);
      float rbx = fminf(bi.z, bj4.z), rby = fminf(bi.w, bj4.w);
      float wv = fmaxf(rbx - ltx, 0.0f), hv = fmaxf(rby - lty, 0.0f);
      float inter = wv * hv;
      float iou = inter / (ia + ja - inter);   // exact: integer-valued fp32
      if (iou > 0.6f) {
        int rj = srank[j];
        atomicOr(&U.M.smaskR[ri * 8 + (rj >> 6)], 1ull << (rj & 63));
      }
    }
  }
  __syncthreads();

  {
    int il = tid >> 3, ww = tid & 7;
    int ig = qi * 128 + il;
    if (ig < n512) {
      int r = srank[ig];
      msk_of(ws, b)[r * 8 + ww] = U.M.smaskR[r * 8 + ww];
      if (ww == 0) krank_of(ws, b)[r] = skey[ig];
    }
  }
}

// ---------------- 256-thread exact radix select (fallback only; no early exits) ----------------
__device__ u64 select256(const u64* keys, int n, int t0, u32* hist, u64* shP, int* shT) {
  u64 Pfx = 3; int t = t0;
  const int SS[4] = {33, 21, 9, 0};
  const int WW[4] = {12, 12, 12, 9};
  for (int p = 0; p < 4; ++p) {
    int s = SS[p], wb = WW[p];
    u32 dmask = (1u << wb) - 1u;
    for (int i = threadIdx.x; i < 4096; i += 256) hist[i] = 0;
    __syncthreads();
    for (int i = threadIdx.x; i < n; i += 256) {
      u64 k = keys[i];
      if ((k >> (s + wb)) == Pfx) atomicAdd(&hist[(u32)(k >> s) & dmask], 1u);
    }
    __syncthreads();
    if (threadIdx.x < 64) {
      int lane = threadIdx.x;
      u32 ssum = 0;
      for (int i = 0; i < 64; ++i) ssum += hist[(lane << 6) + ((i + lane) & 63)];
      u32 inc = ssum;
      for (int o = 1; o < 64; o <<= 1) { u32 v = __shfl_up(inc, o); if (lane >= o) inc += v; }
      u64 ball = __ballot(inc >= (u32)t);
      int Wq = __ffsll(ball) - 1;
      u32 cumBefore = __shfl(inc - ssum, Wq);
      u32 v2 = hist[(Wq << 6) + lane];
      u32 inc2 = v2;
      for (int o = 1; o < 64; o <<= 1) { u32 x = __shfl_up(inc2, o); if (lane >= o) inc2 += x; }
      u64 ball2 = __ballot(cumBefore + inc2 >= (u32)t);
      int l2 = __ffsll(ball2) - 1;
      u32 cumB2 = __shfl(cumBefore + inc2 - v2, l2);
      if (lane == 0) { *shP = (Pfx << wb) | (u32)((Wq << 6) + l2); *shT = t - (int)cumB2; }
    }
    __syncthreads();
    Pfx = *shP; t = *shT;
    __syncthreads();
  }
  return Pfx;   // final pass (s=0) yields the full 47-bit key
}

// ---------------- K3: greedy ffs walk + fallback + slotkey (grid 16, 256 thr) ----------------
__global__ __launch_bounds__(256) void k_reduce(Ptrs P) {
  __shared__ u64 smask[4096];       // 32 KB
  __shared__ u32 keeplist[100];     // ranks (walk phase only)
  __shared__ int keptS;
  __shared__ u64 liveC[267];        // fallback: live bits over gid space
  __shared__ union UF {
    u32 hist[4096];                 // 16 KB (fallback selects)
    struct { u64 pk[256]; int pc[256]; float4 fkb[100]; } F;
  } UF_;
  __shared__ u64 shP; __shared__ int shT;
  __shared__ u64 bk; __shared__ int bc2;

  int b = blockIdx.x;
  int tid = threadIdx.x;
  char* ws = P.ws;
  int n512 = ((int*)(ws + NC_OFF))[16 + b];
  const u64* kr = krank_of(ws, b);

  const u64* gmask = msk_of(ws, b);
  for (int t = tid; t < 4096; t += 256) smask[t] = gmask[t];
  __syncthreads();

  // single-wave barrier-free greedy walk over ranks [0, n512)
  if (tid < 64) {
    int lane = tid;
    u64 lw = 0;
    if (lane < 8) {
      int lo = lane << 6;
      int c = n512 - lo; if (c < 0) c = 0; if (c > 64) c = 64;
      lw = (c >= 64) ? ALLF : ((c > 0) ? ((1ull << c) - 1ull) : 0ull);
    }
    int kept = 0;
    while (kept < 100) {
      bool nz = (lane < 8) && (lw != 0ull);
      u64 bal = __ballot(nz);
      if (!bal) break;
      int W = __ffsll(bal) - 1;
      u64 wv = __shfl(lw, W);
      int bit = __ffsll(wv) - 1;
      int i = (W << 6) + bit;
      if (lane == 0) keeplist[kept] = (u32)i;
      kept++;
      if (lane == W) lw &= ~(1ull << bit);
      if (kept == 100) break;
      if (lane < 8) lw &= ~smask[i * 8 + lane];
    }
    if (lane == 0) keptS = kept;
  }
  __syncthreads();
  int kept = keptS;
  int keptW = kept;

  // fallback: keeps beyond the prefix (rare; exact)
  if (kept < 100) {
    u64 T0 = select256((const u64*)(ws + KEYS0_OFF) + (size_t)b * 12800, 12800, 1000,
                       UF_.hist, &shP, &shT);
    u64 T1 = select256((const u64*)(ws + KEYS1_OFF) + (size_t)b * 3200, 3200, 1000,
                       UF_.hist, &shP, &shT);
    u64 T512 = ((u64*)(ws + T512_OFF))[b];
    for (int w = tid; w < 267; w += 256) {
      int lo = w << 6;
      u64 m = 0;
      for (int e = 0; e < 64; ++e) {
        int u = lo + e;
        if (u < TOTAL_G) {
          u64 k = loadkey(P, b, u);
          if (keep_pred(k, u, T0, T1) && k > T512) m |= (1ull << e);
        }
      }
      liveC[w] = m;
    }
    if (tid < kept) UF_.F.fkb[tid] = decode_box(P, b, (int)(kr[keeplist[tid]] & 0x7FFF));
    __syncthreads();

    // seed suppression from already-kept items
    for (int k2 = 0; k2 < kept; ++k2) {
      float4 bi = UF_.F.fkb[k2];
      float ia = (bi.z - bi.x) * (bi.w - bi.y);
      for (int u = tid; u < TOTAL_G; u += 256) {
        if (!((liveC[u >> 6] >> (u & 63)) & 1ull)) continue;
        float4 bj4 = decode_box(P, b, u);
        float ja  = (bj4.z - bj4.x) * (bj4.w - bj4.y);
        float ltx = fmaxf(bi.x, bj4.x), lty = fmaxf(bi.y, bj4.y);
        float rbx = fminf(bi.z, bj4.z), rby = fminf(bi.w, bj4.w);
        float wv = fmaxf(rbx - ltx, 0.0f), hv = fmaxf(rby - lty, 0.0f);
        float inter = wv * hv;
        float iou = inter / (ia + ja - inter);
        if (iou > 0.6f) atomicAnd(&liveC[u >> 6], ~(1ull << (u & 63)));
      }
    }
    __syncthreads();

    // selection-by-min-key loop
    while (kept < 100) {
      u64 mymin = ALLF; int myc = -1;
      for (int u = tid; u < TOTAL_G; u += 256) {
        if (!((liveC[u >> 6] >> (u & 63)) & 1ull)) continue;
        u64 k = loadkey(P, b, u);
        if (k < mymin) { mymin = k; myc = u; }
      }
      UF_.F.pk[tid] = mymin; UF_.F.pc[tid] = myc;
      __syncthreads();
      if (tid < 64) {
        u64 m = UF_.F.pk[tid]; int c0 = UF_.F.pc[tid];
        #pragma unroll
        for (int o = 64; o < 256; o += 64)
          if (UF_.F.pk[tid + o] < m) { m = UF_.F.pk[tid + o]; c0 = UF_.F.pc[tid + o]; }
        for (int o = 32; o > 0; o >>= 1) {
          u64 om = __shfl_down(m, o); int oc = __shfl_down(c0, o);
          if (om < m) { m = om; c0 = oc; }
        }
        if (tid == 0) { bk = m; bc2 = c0; }
      }
      __syncthreads();
      if (bk == ALLF) break;
      int cs = bc2;
      if (tid == 0) {
        slotkey_of(ws, b)[kept] = bk;     // fallback keeps write slotkey directly
        atomicAnd(&liveC[cs >> 6], ~(1ull << (cs & 63)));
      }
      __syncthreads();
      kept++;
      if (kept == 100) break;
      float4 bi = decode_box(P, b, cs);
      float ia = (bi.z - bi.x) * (bi.w - bi.y);
      for (int u = tid; u < TOTAL_G; u += 256) {
        if (!((liveC[u >> 6] >> (u & 63)) & 1ull)) continue;
        float4 bj4 = decode_box(P, b, u);
        float ja  = (bj4.z - bj4.x) * (bj4.w - bj4.y);
        float ltx = fmaxf(bi.x, bj4.x), lty = fmaxf(bi.y, bj4.y);
        float rbx = fminf(bi.z, bj4.z), rby = fminf(bi.w, bj4.w);
        float wv = fmaxf(rbx - ltx, 0.0f), hv = fmaxf(rby - lty, 0.0f);
        float inter = wv * hv;
        float iou = inter / (ia + ja - inter);
        if (iou > 0.6f) atomicAnd(&liveC[u >> 6], ~(1ull << (u & 63)));
      }
      __syncthreads();
    }
  }

  // resolve slot keys: walk entries via kr; fallback entries already written; rest = ALLF
  if (tid < 100) {
    if (tid < keptW)      slotkey_of(ws, b)[tid] = kr[keeplist[tid]];
    else if (tid >= kept) slotkey_of(ws, b)[tid] = ALLF;
  }
}

// ---------------- K4: parallel outputs (grid 16 x 10, 256 thr) ----------------
__global__ __launch_bounds__(256) void k_out(Ptrs P, float* out) {
  int b = blockIdx.x, part = blockIdx.y;   // 10 slots per block
  int s0 = part * 10;
  int tid = threadIdx.x;
  const u64* skl = slotkey_of(P.ws, b);

  if (tid < 10) {
    int s = s0 + tid;
    u64 key = skl[s];
    float os = -1.0f, oc = -1.0f;
    float4 bx = make_float4(-1.0f, -1.0f, -1.0f, -1.0f);
    if (key != ALLF) {
      int gid = (int)(key & 0x7FFF);
      os = __uint_as_float(~(u32)(key >> 15));
      oc = (float)((u16*)(P.ws + CLSI_OFF))[(size_t)b * TOTAL_G + gid];
      bx = decode_box(P, b, gid);
    }
    out[b * 100 + s] = os;
    out[1600 + b * 100 + s] = oc;
    *(float4*)(out + 3200 + (size_t)(b * 100 + s) * 4) = bx;
  }

  for (int t = tid; t < 800; t += 256) {
    int sl = t / 80, k = t - sl * 80;
    int s = s0 + sl;
    u64 key = skl[s];
    float val = -1.0f;
    if (key != ALLF) {
      int gid = (int)(key & 0x7FFF);
      int lev, idx, nl; levinfo(gid, lev, idx, nl);
      const float* cp;
      if      (lev == 0) cp = P.cls0;
      else if (lev == 1) cp = P.cls1;
      else if (lev == 2) cp = P.cls2;
      else if (lev == 3) cp = P.cls3;
      else               cp = P.cls4;
      val = sigd(cp[(size_t)(b * nl + idx) * 80 + k]);
    }
    out[9600 + (size_t)(b * 100 + s) * 80 + k] = val;
  }
}

extern "C" void kernel_launch(void* const* d_in, const int* in_sizes, int n_in,
                              void* d_out, int out_size, void* d_ws, size_t ws_size,
                              hipStream_t stream) {
  (void)in_sizes; (void)n_in; (void)out_size; (void)ws_size;
  Ptrs P;
  P.cls0 = (const float*)d_in[0];  P.reg0 = (const float*)d_in[1];
  P.ctr0 = (const float*)d_in[2];  P.pos0 = (const float*)d_in[3];
  P.cls1 = (const float*)d_in[4];  P.reg1 = (const float*)d_in[5];
  P.ctr1 = (const float*)d_in[6];  P.pos1 = (const float*)d_in[7];
  P.cls2 = (const float*)d_in[8];  P.reg2 = (const float*)d_in[9];
  P.ctr2 = (const float*)d_in[10]; P.pos2 = (const float*)d_in[11];
  P.cls3 = (const float*)d_in[12]; P.reg3 = (const float*)d_in[13];
  P.ctr3 = (const float*)d_in[14]; P.pos3 = (const float*)d_in[15];
  P.cls4 = (const float*)d_in[16]; P.reg4 = (const float*)d_in[17];
  P.ctr4 = (const float*)d_in[18]; P.pos4 = (const float*)d_in[19];
  P.ws = (char*)d_ws;

  k_score<<<dim3(267, 16), 256, 0, stream>>>(P);
  k_mask<<<dim3(4, 16), 1024, 0, stream>>>(P);
  k_reduce<<<16, 256, 0, stream>>>(P);
  k_out<<<dim3(16, 10), 256, 0, stream>>>(P, (float*)d_out);
}